// Round 6
// baseline (1135.234 us; speedup 1.0000x reference)
//
#include <hip/hip_runtime.h>

typedef __attribute__((ext_vector_type(8))) short bf16x8;
typedef __attribute__((ext_vector_type(4))) float f32x4;
typedef __attribute__((ext_vector_type(2))) float f32x2;
typedef __attribute__((ext_vector_type(4))) unsigned int u32x4;
typedef unsigned short ushort_t;

__device__ inline ushort_t bf16_trunc(float f) { return (ushort_t)(__float_as_uint(f) >> 16); }
__device__ inline float bf16_to_f(ushort_t u) { return __uint_as_float(((unsigned int)u) << 16); }

// packed fp32 (CDNA3+): two IEEE fp32 ops per instruction
__device__ inline f32x2 pk_mul(f32x2 a, f32x2 b) {
    f32x2 d;
    asm("v_pk_mul_f32 %0, %1, %2" : "=v"(d) : "v"(a), "v"(b));
    return d;
}
__device__ inline f32x2 pk_fma(f32x2 a, f32x2 b, f32x2 c) {
    f32x2 d;
    asm("v_pk_fma_f32 %0, %1, %2, %3" : "=v"(d) : "v"(a), "v"(b), "v"(c));
    return d;
}

// pack top-16-bits of two fp32 into one u32: (u0>>16) | (u1 & 0xffff0000)
__device__ inline unsigned int hi_pair(unsigned int u1, unsigned int u0) {
    return __builtin_amdgcn_perm(u1, u0, 0x07060302u);
}

// split 8 fp32 (sA,sB) into bf16 hi + bf16 lo fragments via v_perm packing
__device__ inline void split8(const f32x4 sA, const f32x4 sB, bf16x8& ahi, bf16x8& alo)
{
    unsigned int u[8], h[8], d[8];
#pragma unroll
    for (int j = 0; j < 4; ++j) {
        u[j]     = __float_as_uint(sA[j]);
        u[4 + j] = __float_as_uint(sB[j]);
    }
#pragma unroll
    for (int j = 0; j < 8; ++j) {
        h[j] = u[j] & 0xffff0000u;                       // exact bf16-hi as f32 bits
        d[j] = __float_as_uint(__uint_as_float(u[j]) - __uint_as_float(h[j]));
    }
    union { u32x4 w; bf16x8 v; } H, L;
    H.w = (u32x4){hi_pair(h[1], h[0]), hi_pair(h[3], h[2]), hi_pair(h[5], h[4]), hi_pair(h[7], h[6])};
    L.w = (u32x4){hi_pair(d[1], d[0]), hi_pair(d[3], d[2]), hi_pair(d[5], d[4]), hi_pair(d[7], d[6])};
    ahi = H.v;
    alo = L.v;
}

// ---------------------------------------------------------------------------
// Weight prep for conv_mfma: OIHW fp32 -> [kk][n][ci] hi/lo, zero-padded.
// ---------------------------------------------------------------------------
template<int CI, int KK, int KKPAD, int NPAD, int OC>
__global__ __launch_bounds__(256)
void wprep(const float* __restrict__ w, ushort_t* __restrict__ bhi, ushort_t* __restrict__ blo)
{
    const int idx = blockIdx.x * 256 + threadIdx.x;
    if (idx >= KKPAD * NPAD * CI) return;
    const int kk  = idx / (NPAD * CI);
    const int rem = idx - kk * (NPAD * CI);
    const int n   = rem / CI;
    const int ci  = rem - n * CI;
    const float v = (kk < KK && n < OC) ? w[((size_t)n * CI + ci) * KK + kk] : 0.f;
    const ushort_t h = bf16_trunc(v);
    bhi[idx] = h;
    blo[idx] = bf16_trunc(v - bf16_to_f(h));
}

// ---------------------------------------------------------------------------
// Weight prep for deform_mfma: pack [kslot = g8*TPAD+tap][n][j=ci_in_group].
// ---------------------------------------------------------------------------
template<int CI, int KK, int TPAD, int NPAD, int OC>
__global__ __launch_bounds__(256)
void wprep_d(const float* __restrict__ w, ushort_t* __restrict__ bhi, ushort_t* __restrict__ blo)
{
    constexpr int NPASS = (CI + 7) / 8;
    constexpr int TOTAL = NPASS * TPAD * NPAD * 8;
    const int idx = blockIdx.x * 256 + threadIdx.x;
    if (idx >= TOTAL) return;
    const int j     = idx & 7;
    const int n     = (idx >> 3) % NPAD;
    const int kslot = (idx >> 3) / NPAD;
    const int pass  = kslot / TPAD;
    const int tap   = kslot - pass * TPAD;
    const int ci    = pass * 8 + j;
    const float v = (tap < KK && n < OC && ci < CI) ? w[((size_t)n * CI + ci) * KK + tap] : 0.f;
    const ushort_t h = bf16_trunc(v);
    bhi[idx] = h;
    blo[idx] = bf16_trunc(v - bf16_to_f(h));
}

// ---------------------------------------------------------------------------
// MFMA implicit-im2col conv, v5: BARRIER-FREE.
//  * B fragments read directly from global (L2-resident, <=205 KB total;
//    a wave's 64 lanes form one contiguous 1 KB read). No LDS B slab ->
//    no __syncthreads -> no per-K-step vmcnt/lgkm drain. Each wave
//    free-runs; compiler pipelines the unrolled K loop.
//  * A fragments stay double-buffered (prefetch one K-step ahead).
// ---------------------------------------------------------------------------
template<int CI, int K, int H, int W, int Ho, int Wo, int OC, int NTTOT, int NT0, int KSTEPS>
__global__ __launch_bounds__(256)
void conv_mfma(const ushort_t* __restrict__ Xhi, const ushort_t* __restrict__ Xlo,
               const ushort_t* __restrict__ Bhi, const ushort_t* __restrict__ Blo,
               const float* __restrict__ bias, float* __restrict__ out, int Mtotal)
{
    constexpr int NPAD = NTTOT * 16;
    constexpr int HW   = H * W;
    constexpr int HoWo = Ho * Wo;
    constexpr int NPASS = CI / 8;

    const int tid  = threadIdx.x;
    const int lane = tid & 63;
    const int wid  = tid >> 6;
    const int col  = lane & 15;
    const int quad = lane >> 4;

    const int mBase  = blockIdx.x * 256 + wid * 64;
    const int ntBase = blockIdx.y * NT0;

    int aBase[4];
#pragma unroll
    for (int mt = 0; mt < 4; ++mt) {
        int mm = mBase + mt * 16 + col;
        if (mm >= Mtotal) mm = Mtotal - 1;
        const int b   = mm / HoWo;
        const int pos = mm - b * HoWo;
        const int oy  = pos / Wo;
        const int ox  = pos - oy * Wo;
        aBase[mt] = b * NPASS * HW + oy * W + ox;
    }

    f32x4 acc[4][NT0];
#pragma unroll
    for (int mt = 0; mt < 4; ++mt)
#pragma unroll
        for (int nt = 0; nt < NT0; ++nt) acc[mt][nt] = (f32x4){0.f, 0.f, 0.f, 0.f};

    // double-buffered A fragments (prefetched one K-step ahead)
    bf16x8 ah[2][4], al[2][4];

    auto loadA = [&](int ks, int pb) {
        const int k0   = ks * 32 + quad * 8;
        const int tap  = k0 / CI;
        const int ci   = k0 - tap * CI;
        const int g    = ci >> 3;
        const int dkk  = (tap / K) * W + (tap - (tap / K) * K);
#pragma unroll
        for (int mt = 0; mt < 4; ++mt) {
            const size_t aoff = (size_t)(aBase[mt] + g * HW + dkk) * 8;
            ah[pb][mt] = *(const bf16x8*)(Xhi + aoff);
            al[pb][mt] = *(const bf16x8*)(Xlo + aoff);
        }
    };

    loadA(0, 0);

#pragma unroll
    for (int ks = 0; ks < KSTEPS; ++ks) {
        if (ks + 1 < KSTEPS) loadA(ks + 1, (ks + 1) & 1);

        const int k0   = ks * 32 + quad * 8;
        const int tap  = k0 / CI;
        const int ci   = k0 - tap * CI;
        const int pb   = ks & 1;

#pragma unroll
        for (int nt = 0; nt < NT0; ++nt) {
            const int ntg = ntBase + nt;
            if (ntg < NTTOT) {
                const size_t boff = ((size_t)tap * NPAD + ntg * 16 + col) * CI + ci;
                const bf16x8 bh = *(const bf16x8*)(Bhi + boff);
                const bf16x8 bl = *(const bf16x8*)(Blo + boff);
#pragma unroll
                for (int mt = 0; mt < 4; ++mt) {
                    acc[mt][nt] = __builtin_amdgcn_mfma_f32_16x16x32_bf16(ah[pb][mt], bh, acc[mt][nt], 0, 0, 0);
                    acc[mt][nt] = __builtin_amdgcn_mfma_f32_16x16x32_bf16(al[pb][mt], bh, acc[mt][nt], 0, 0, 0);
                    acc[mt][nt] = __builtin_amdgcn_mfma_f32_16x16x32_bf16(ah[pb][mt], bl, acc[mt][nt], 0, 0, 0);
                }
            }
        }
    }

#pragma unroll
    for (int mt = 0; mt < 4; ++mt) {
#pragma unroll
        for (int nt = 0; nt < NT0; ++nt) {
            const int ntg = ntBase + nt;
            const int n   = ntg * 16 + col;
            if (ntg < NTTOT && n < OC) {
                const float bv = bias[n];
#pragma unroll
                for (int r = 0; r < 4; ++r) {
                    const int m = mBase + mt * 16 + quad * 4 + r;
                    if (m < Mtotal) {
                        const int b   = m / HoWo;
                        const int pos = m - b * HoWo;
                        out[((size_t)b * OC + n) * HoWo + pos] = acc[mt][nt][r] + bv;
                    }
                }
            }
        }
    }
}

// ---------------------------------------------------------------------------
// MFMA deformable conv (stages 2-5), v6: single-pass staging + packed-fp32
// interp + dead-wave skip. [r5 measured: kernel internals neutral-positive;
// TLP-bound on LDS gather — model 122 µs vs 131.6 measured @ stage 3.]
// ---------------------------------------------------------------------------
template<int K, int CI, int CO, int H, int W, int Ho, int Wo, bool RELU,
         int MT, int TPAD, bool OUTPL>
__global__ __launch_bounds__(MT * 64, 4)
void deform_mfma(const ushort_t* __restrict__ Xhi, const ushort_t* __restrict__ Xlo,
                 const float* __restrict__ off,
                 const ushort_t* __restrict__ Bph, const ushort_t* __restrict__ Bpl,
                 const float* __restrict__ bias,
                 float* __restrict__ outF, ushort_t* __restrict__ oHi, ushort_t* __restrict__ oLo)
{
    static_assert(CI % 8 == 0, "channel-grouped layout requires CI % 8 == 0");
    constexpr int KK     = K * K;
    constexpr int HW     = H * W;
    constexpr int HoWo   = Ho * Wo;
    constexpr int GP     = CI / 8;          // 8-channel groups, all staged at once
    constexpr int NPO    = CO / 8;
    constexpr int NT     = (CO + 15) / 16;
    constexpr int NPAD   = NT * 16;
    constexpr int TSTR   = CI + 4;          // floats per position (mult of 4)
    constexpr int TG     = TPAD / 4;
    constexpr int nMB    = (HoWo + MT * 16 - 1) / (MT * 16);
    constexpr int THREADS = MT * 64;
    __shared__ __align__(16) float tile[HW * TSTR];

    const int b    = blockIdx.x / nMB;
    const int mb   = blockIdx.x - b * nMB;
    const int tid  = threadIdx.x;
    const int wid  = tid >> 6;
    const int lane = tid & 63;
    const int col  = lane & 15;
    const int quad = lane >> 4;

    const int pixel0 = (mb * MT + wid) * 16;
    const int s      = pixel0 + col;
    const bool am    = (s < HoWo);
    const int oy = s / Wo, ox = s - oy * Wo;

    const float* offB = off + (size_t)b * 2 * KK * HoWo;

    f32x4 acc[NT];
#pragma unroll
    for (int nt = 0; nt < NT; ++nt) acc[nt] = (f32x4){0.f, 0.f, 0.f, 0.f};

    // ---- stage the full CI-channel input image into LDS (one pass) ----
    for (int pos = tid; pos < HW; pos += THREADS) {
        float* tp = tile + pos * TSTR;
#pragma unroll
        for (int g = 0; g < GP; ++g) {
            const size_t gbase = ((size_t)(b * GP + g) * HW + pos) * 8;
            const bf16x8 h8 = *(const bf16x8*)(Xhi + gbase);
            const bf16x8 l8 = *(const bf16x8*)(Xlo + gbase);
            f32x4 vA, vB;
#pragma unroll
            for (int j = 0; j < 4; ++j) {
                vA[j] = bf16_to_f((ushort_t)h8[j])     + bf16_to_f((ushort_t)l8[j]);
                vB[j] = bf16_to_f((ushort_t)h8[4 + j]) + bf16_to_f((ushort_t)l8[4 + j]);
            }
            *(f32x4*)(tp + g * 8)     = vA;
            *(f32x4*)(tp + g * 8 + 4) = vB;
        }
    }
    __syncthreads();

    if (pixel0 < HoWo) {      // dead-wave skip (wave-uniform; no barrier below)
#pragma unroll
        for (int tg = 0; tg < TG; ++tg) {
            const int tap = tg * 4 + quad;

            float w00 = 0.f, w01 = 0.f, w10 = 0.f, w11 = 0.f;
            int   i00 = 0,   i01 = 0,   i10 = 0,   i11 = 0;

            if (am && tap < KK) {
                const float dy = offB[(size_t)(2 * tap + 0) * HoWo + s];
                const float dx = offB[(size_t)(2 * tap + 1) * HoWo + s];
                const float py = (float)(tap / K + oy) + dy;
                const float px = (float)(tap % K + ox) + dx;
                const float y0f = floorf(py), x0f = floorf(px);
                const float wy = py - y0f, wx = px - x0f;
                const int y0 = (int)y0f, x0 = (int)x0f;
                const int y1 = y0 + 1,   x1 = x0 + 1;

                const float m00 = (y0 >= 0 && y0 < H && x0 >= 0 && x0 < W) ? 1.f : 0.f;
                const float m01 = (y0 >= 0 && y0 < H && x1 >= 0 && x1 < W) ? 1.f : 0.f;
                const float m10 = (y1 >= 0 && y1 < H && x0 >= 0 && x0 < W) ? 1.f : 0.f;
                const float m11 = (y1 >= 0 && y1 < H && x1 >= 0 && x1 < W) ? 1.f : 0.f;

                w00 = (1.f - wy) * (1.f - wx) * m00;
                w01 = (1.f - wy) * wx         * m01;
                w10 = wy         * (1.f - wx) * m10;
                w11 = wy         * wx         * m11;

                const int y0c = min(max(y0, 0), H - 1), y1c = min(max(y1, 0), H - 1);
                const int x0c = min(max(x0, 0), W - 1), x1c = min(max(x1, 0), W - 1);
                i00 = (y0c * W + x0c) * TSTR;
                i01 = (y0c * W + x1c) * TSTR;
                i10 = (y1c * W + x0c) * TSTR;
                i11 = (y1c * W + x1c) * TSTR;
            }

            const f32x2 w00p = {w00, w00}, w01p = {w01, w01};
            const f32x2 w10p = {w10, w10}, w11p = {w11, w11};

#pragma unroll
            for (int g = 0; g < GP; ++g) {
                const float* tp = tile + g * 8;
                const f32x4 a00 = *(const f32x4*)(tp + i00);
                const f32x4 c00 = *(const f32x4*)(tp + i00 + 4);
                const f32x4 a01 = *(const f32x4*)(tp + i01);
                const f32x4 c01 = *(const f32x4*)(tp + i01 + 4);
                const f32x4 a10 = *(const f32x4*)(tp + i10);
                const f32x4 c10 = *(const f32x4*)(tp + i10 + 4);
                const f32x4 a11 = *(const f32x4*)(tp + i11);
                const f32x4 c11 = *(const f32x4*)(tp + i11 + 4);

#define LOH(v) __builtin_shufflevector(v, v, 0, 1)
#define HIH(v) __builtin_shufflevector(v, v, 2, 3)
                f32x2 sA0 = pk_mul(LOH(a00), w00p);
                sA0 = pk_fma(LOH(a01), w01p, sA0);
                sA0 = pk_fma(LOH(a10), w10p, sA0);
                sA0 = pk_fma(LOH(a11), w11p, sA0);
                f32x2 sA1 = pk_mul(HIH(a00), w00p);
                sA1 = pk_fma(HIH(a01), w01p, sA1);
                sA1 = pk_fma(HIH(a10), w10p, sA1);
                sA1 = pk_fma(HIH(a11), w11p, sA1);
                f32x2 sB0 = pk_mul(LOH(c00), w00p);
                sB0 = pk_fma(LOH(c01), w01p, sB0);
                sB0 = pk_fma(LOH(c10), w10p, sB0);
                sB0 = pk_fma(LOH(c11), w11p, sB0);
                f32x2 sB1 = pk_mul(HIH(c00), w00p);
                sB1 = pk_fma(HIH(c01), w01p, sB1);
                sB1 = pk_fma(HIH(c10), w10p, sB1);
                sB1 = pk_fma(HIH(c11), w11p, sB1);
#undef LOH
#undef HIH
                const f32x4 sA = __builtin_shufflevector(sA0, sA1, 0, 1, 2, 3);
                const f32x4 sB = __builtin_shufflevector(sB0, sB1, 0, 1, 2, 3);

                bf16x8 ahi, alo;
                split8(sA, sB, ahi, alo);

                const int kslot = g * TPAD + tap;
#pragma unroll
                for (int nt = 0; nt < NT; ++nt) {
                    const bf16x8 bh = *(const bf16x8*)(Bph + ((size_t)kslot * NPAD + nt * 16 + col) * 8);
                    const bf16x8 bl = *(const bf16x8*)(Bpl + ((size_t)kslot * NPAD + nt * 16 + col) * 8);
                    acc[nt] = __builtin_amdgcn_mfma_f32_16x16x32_bf16(ahi, bh, acc[nt], 0, 0, 0);
                    acc[nt] = __builtin_amdgcn_mfma_f32_16x16x32_bf16(alo, bh, acc[nt], 0, 0, 0);
                    acc[nt] = __builtin_amdgcn_mfma_f32_16x16x32_bf16(ahi, bl, acc[nt], 0, 0, 0);
                }
            }
        }
    }

#pragma unroll
    for (int nt = 0; nt < NT; ++nt) {
        const int n = nt * 16 + col;
        if (n < CO) {
            const float bv = bias[n];
#pragma unroll
            for (int r = 0; r < 4; ++r) {
                const int m = pixel0 + quad * 4 + r;
                if (m < HoWo) {
                    float v = acc[nt][r] + bv;
                    if (RELU) v = fmaxf(v, 0.f);
                    if (OUTPL) {
                        const size_t o = (((size_t)b * NPO + (n >> 3)) * HoWo + m) * 8 + (n & 7);
                        const ushort_t h = bf16_trunc(v);
                        oHi[o] = h;
                        oLo[o] = bf16_trunc(v - bf16_to_f(h));
                    } else {
                        outF[((size_t)b * CO + n) * HoWo + m] = v;
                    }
                }
            }
        }
    }
}

// ---------------------------------------------------------------------------
// Scalar LDS deform (stages 1 and 6). Reads fp32 NCHW. Epilogue writes
// grouped planes (OUTPL, stage 1) or fp32 NCHW (stage 6).
// ---------------------------------------------------------------------------
template<int K, int CI, int CO, int H, int W, int Ho, int Wo, bool RELU,
         int CSPLIT, int STRIDE, int THREADS, int SPLIT, bool OUTPL>
__global__ __launch_bounds__(THREADS)
void deform_lds(const float* __restrict__ x, const float* __restrict__ off,
                const float* __restrict__ w, const float* __restrict__ bias,
                float* __restrict__ outF, ushort_t* __restrict__ oHi, ushort_t* __restrict__ oLo)
{
    constexpr int KK    = K * K;
    constexpr int HW    = H * W;
    constexpr int HoWo  = Ho * Wo;
    constexpr int NPASS = CI / CSPLIT;
    constexpr int NPO   = (CO + 7) / 8;
    constexpr int CHUNK = (HoWo + SPLIT - 1) / SPLIT;
    static_assert(CHUNK <= THREADS, "chunk must fit in one block");
    __shared__ __align__(16) float tile[HW * STRIDE];

    const int b   = blockIdx.x / SPLIT;
    const int sp  = blockIdx.x - b * SPLIT;
    const int tid = threadIdx.x;
    const int s   = sp * CHUNK + tid;
    const bool active = (tid < CHUNK) && (s < HoWo);

    const int oy = s / Wo, ox = s - oy * Wo;
    const float* offp = off + ((size_t)b * 2 * KK) * HoWo + s;

    float acc[CO];
#pragma unroll
    for (int o = 0; o < CO; ++o) acc[o] = 0.f;

    for (int pass = 0; pass < NPASS; ++pass) {
        const int cbase = pass * CSPLIT;
        __syncthreads();
        for (int pos = tid; pos < HW; pos += THREADS) {
#pragma unroll
            for (int c = 0; c < CSPLIT; ++c)
                tile[pos * STRIDE + c] = x[((size_t)b * CI + (cbase + c)) * HW + pos];
        }
        __syncthreads();

        if (active) {
            for (int kk = 0; kk < KK; ++kk) {
                const float dy = offp[(size_t)(2 * kk + 0) * HoWo];
                const float dx = offp[(size_t)(2 * kk + 1) * HoWo];
                const float py = (float)(kk / K + oy) + dy;
                const float px = (float)(kk % K + ox) + dx;
                const float y0f = floorf(py), x0f = floorf(px);
                const float wy = py - y0f, wx = px - x0f;
                const int y0 = (int)y0f, x0 = (int)x0f;
                const int y1 = y0 + 1,   x1 = x0 + 1;

                const float m00 = (y0 >= 0 && y0 < H && x0 >= 0 && x0 < W) ? 1.f : 0.f;
                const float m01 = (y0 >= 0 && y0 < H && x1 >= 0 && x1 < W) ? 1.f : 0.f;
                const float m10 = (y1 >= 0 && y1 < H && x0 >= 0 && x0 < W) ? 1.f : 0.f;
                const float m11 = (y1 >= 0 && y1 < H && x1 >= 0 && x1 < W) ? 1.f : 0.f;

                const float w00 = (1.f - wy) * (1.f - wx) * m00;
                const float w01 = (1.f - wy) * wx         * m01;
                const float w10 = wy         * (1.f - wx) * m10;
                const float w11 = wy         * wx         * m11;

                const int y0c = min(max(y0, 0), H - 1), y1c = min(max(y1, 0), H - 1);
                const int x0c = min(max(x0, 0), W - 1), x1c = min(max(x1, 0), W - 1);
                const int i00 = (y0c * W + x0c) * STRIDE;
                const int i01 = (y0c * W + x1c) * STRIDE;
                const int i10 = (y1c * W + x0c) * STRIDE;
                const int i11 = (y1c * W + x1c) * STRIDE;

                if constexpr (CSPLIT % 4 == 0) {
#pragma unroll
                    for (int cg = 0; cg < CSPLIT; cg += 4) {
                        const f32x4 v00 = *(const f32x4*)(tile + i00 + cg);
                        const f32x4 v01 = *(const f32x4*)(tile + i01 + cg);
                        const f32x4 v10 = *(const f32x4*)(tile + i10 + cg);
                        const f32x4 v11 = *(const f32x4*)(tile + i11 + cg);
#pragma unroll
                        for (int j = 0; j < 4; ++j) {
                            const float sv = fmaf(v11[j], w11, fmaf(v10[j], w10,
                                             fmaf(v01[j], w01, v00[j] * w00)));
#pragma unroll
                            for (int o = 0; o < CO; ++o)
                                acc[o] = fmaf(sv, w[(size_t)(o * CI + cbase + cg + j) * KK + kk], acc[o]);
                        }
                    }
                } else {
                    const float sv = fmaf(tile[i11], w11, fmaf(tile[i10], w10,
                                     fmaf(tile[i01], w01, tile[i00] * w00)));
#pragma unroll
                    for (int o = 0; o < CO; ++o)
                        acc[o] = fmaf(sv, w[(size_t)(o * CI + cbase) * KK + kk], acc[o]);
                }
            }
        }
    }

    if (active) {
#pragma unroll
        for (int o = 0; o < CO; ++o) {
            float v = acc[o] + bias[o];
            if (RELU) v = fmaxf(v, 0.f);
            if (OUTPL) {
                const size_t oi = (((size_t)b * NPO + (o >> 3)) * HoWo + s) * 8 + (o & 7);
                const ushort_t h = bf16_trunc(v);
                oHi[oi] = h;
                oLo[oi] = bf16_trunc(v - bf16_to_f(h));
            } else {
                outF[((size_t)b * CO + o) * HoWo + s] = v;
            }
        }
    }
}

// ---------------------------------------------------------------------------
// Register-tiled direct VALID conv (stages 1 and 6 offset convs).
// ---------------------------------------------------------------------------
template<int K, int CI, int NOC, int OC, int H, int W, int Ho, int Wo, int PIX>
__global__ __launch_bounds__(256)
void conv_tile(const float* __restrict__ x, const float* __restrict__ w,
               const float* __restrict__ bias, float* __restrict__ out)
{
    constexpr int KK   = K * K;
    constexpr int HoWo = Ho * Wo;
    constexpr int WoG  = (Wo + PIX - 1) / PIX;
    constexpr int G    = Ho * WoG;
    constexpr int XV   = PIX + K - 1;

    const int oc0   = blockIdx.y * NOC;
    const int g_all = blockIdx.x * 256 + threadIdx.x;
    const int b     = g_all / G;
    const int g     = g_all - b * G;
    const int oy    = g / WoG;
    const int ox0   = (g - oy * WoG) * PIX;

    const float* xbp = x + (b * CI) * (H * W) + oy * W + ox0;
    const float* wp  = w + oc0 * (CI * KK);

    float acc[PIX][NOC];
#pragma unroll
    for (int p = 0; p < PIX; ++p)
#pragma unroll
        for (int j = 0; j < NOC; ++j) acc[p][j] = bias[oc0 + j];

    const int lim = W - 1 - ox0;

    for (int ci = 0; ci < CI; ++ci) {
        const float* xc = xbp + ci * (H * W);
#pragma unroll
        for (int ky = 0; ky < K; ++ky) {
            float xv[XV];
#pragma unroll
            for (int i = 0; i < XV; ++i) {
                const int off = (i <= lim) ? i : lim;
                xv[i] = xc[ky * W + off];
            }
#pragma unroll
            for (int kx = 0; kx < K; ++kx) {
#pragma unroll
                for (int p = 0; p < PIX; ++p) {
                    const float v = xv[p + kx];
#pragma unroll
                    for (int j = 0; j < NOC; ++j)
                        acc[p][j] = fmaf(v, wp[j * (CI * KK) + ci * KK + ky * K + kx], acc[p][j]);
                }
            }
        }
    }

    float* op = out + (b * OC + oc0) * HoWo + oy * Wo + ox0;
#pragma unroll
    for (int p = 0; p < PIX; ++p) {
        if (ox0 + p < Wo) {
#pragma unroll
            for (int j = 0; j < NOC; ++j) op[j * HoWo + p] = acc[p][j];
        }
    }
}

// ---------------------------------------------------------------------------
// FC weight transpose + coalesced FC.
// ---------------------------------------------------------------------------
template<int IN, int OUT>
__global__ __launch_bounds__(256)
void wtrans(const float* __restrict__ w, float* __restrict__ wt)
{
    const int idx = blockIdx.x * 256 + threadIdx.x;
    if (idx >= IN * OUT) return;
    const int i = idx / OUT, j = idx - i * OUT;
    wt[idx] = w[(size_t)j * IN + i];
}

template<int IN, int OUT, bool RELU>
__global__ __launch_bounds__(256)
void fc_t(const float* __restrict__ h, const float* __restrict__ wt,
          const float* __restrict__ bias, float* __restrict__ out, int B)
{
    const int idx = blockIdx.x * 256 + threadIdx.x;
    if (idx >= B * OUT) return;
    const int b = idx / OUT;
    const int j = idx - b * OUT;
    const float* hb = h + (size_t)b * IN;
    float acc = bias[j];
#pragma unroll 4
    for (int i = 0; i < IN; ++i)
        acc = fmaf(hb[i], wt[(size_t)i * OUT + j], acc);
    if (RELU) acc = fmaxf(acc, 0.f);
    out[idx] = acc;
}

// ---------------------------------------------------------------------------
extern "C" void kernel_launch(void* const* d_in, const int* in_sizes, int n_in,
                              void* d_out, int out_size, void* d_ws, size_t ws_size,
                              hipStream_t stream)
{
    const int B = 512;
    const float* x = (const float*)d_in[0];
    const float *ow[6], *ob[6], *w[6], *bi[6];
    for (int i = 0; i < 6; ++i) {
        ow[i] = (const float*)d_in[1 + 4 * i];
        ob[i] = (const float*)d_in[2 + 4 * i];
        w[i]  = (const float*)d_in[3 + 4 * i];
        bi[i] = (const float*)d_in[4 + 4 * i];
    }
    const float* fc1w = (const float*)d_in[25];
    const float* fc1b = (const float*)d_in[26];
    const float* fc2w = (const float*)d_in[27];
    const float* fc2b = (const float*)d_in[28];
    float* out = (float*)d_out;

    float* P   = (float*)d_ws;        // 14M floats
    float* Q   = P  + 14000000;       // 14M floats
    float* OFF = Q  + 14000000;       // 18.2M floats
    float* Z   = OFF + 18200000;      // fc intermediate
    ushort_t* WBhi = (ushort_t*)(Z + 200000);
    ushort_t* WBlo = WBhi + 200000;
    ushort_t* WDhi = WBlo + 200000;
    ushort_t* WDlo = WDhi + 200000;
    float* WT1 = (float*)(WDlo + 200000);
    float* WT2 = WT1 + 173056;

    const dim3 blk(256);
    #define GRIDT(Ho, Wo, PIX, NG) dim3((B * (Ho) * (((Wo) + (PIX) - 1) / (PIX)) + 255) / 256, (NG), 1)
    #define CEILDIV(a, b) (((a) + (b) - 1) / (b))

    // plane regions (channel-grouped layout)
    ushort_t* PL2h = (ushort_t*)Q;  ushort_t* PL2l = PL2h + (size_t)(B * 961 + 2048) * 16;
    ushort_t* PL3h = (ushort_t*)P;  ushort_t* PL3l = PL3h + (size_t)(B * 841 + 2048) * 32;
    ushort_t* PL4h = (ushort_t*)Q;  ushort_t* PL4l = PL4h + (size_t)(B * 625 + 2048) * 16;
    ushort_t* PL5h = (ushort_t*)P;  ushort_t* PL5l = PL5h + (size_t)(B * 361 + 2048) * 16;

    // ---- stage 1: input x (CI=1). conv_tile -> OFF; deform_lds -> PL2 ----
    conv_tile<3, 1, 6, 18, 33, 33, 31, 31, 4><<<GRIDT(31, 31, 4, 3), blk, 0, stream>>>(x, ow[0], ob[0], OFF);
    deform_lds<3, 1, 16, 33, 33, 31, 31, true, 1, 1, 512, 2, true><<<dim3(B * 2), dim3(512), 0, stream>>>(x, OFF, w[0], bi[0], nullptr, PL2h, PL2l);

    // ---- stage 2: CI=16 K=3 31x31->29x29 OC(off)=18 CO=32. PL2 -> PL3 ----
    {
        const int Mv = B * 841;
        wprep<16, 9, 10, 32, 18><<<CEILDIV(10 * 32 * 16, 256), blk, 0, stream>>>(ow[1], WBhi, WBlo);
        conv_mfma<16, 3, 31, 31, 29, 29, 18, 2, 2, 5><<<dim3(CEILDIV(Mv, 256), 1), blk, 0, stream>>>(PL2h, PL2l, WBhi, WBlo, ob[1], OFF, Mv);
        wprep_d<16, 9, 12, 32, 32><<<CEILDIV(2 * 12 * 32 * 8, 256), blk, 0, stream>>>(w[1], WDhi, WDlo);
        deform_mfma<3, 16, 32, 31, 31, 29, 29, true, 8, 12, true><<<dim3(B * 7), dim3(512), 0, stream>>>(PL2h, PL2l, OFF, WDhi, WDlo, bi[1], nullptr, PL3h, PL3l);
    }
    // ---- stage 3: CI=32 K=5 29x29->25x25 OC(off)=50 CO=16 (no relu). PL3 -> PL4 ----
    // single-pass (121 KB LDS), MT=14: measured-best config
    {
        const int Mv = B * 625;
        wprep<32, 25, 25, 64, 50><<<CEILDIV(25 * 64 * 32, 256), blk, 0, stream>>>(ow[2], WBhi, WBlo);
        conv_mfma<32, 5, 29, 29, 25, 25, 50, 4, 4, 25><<<dim3(CEILDIV(Mv, 256), 1), blk, 0, stream>>>(PL3h, PL3l, WBhi, WBlo, ob[2], OFF, Mv);
        wprep_d<32, 25, 28, 16, 16><<<CEILDIV(4 * 28 * 16 * 8, 256), blk, 0, stream>>>(w[2], WDhi, WDlo);
        deform_mfma<5, 32, 16, 29, 29, 25, 25, false, 14, 28, true><<<dim3(B * 3), dim3(896), 0, stream>>>(PL3h, PL3l, OFF, WDhi, WDlo, bi[2], nullptr, PL4h, PL4l);
    }
    // ---- stage 4: CI=16 K=7 25x25->19x19 OC(off)=98 CO=16. PL4 -> PL5 ----
    {
        const int Mv = B * 361;
        wprep<16, 49, 50, 112, 98><<<CEILDIV(50 * 112 * 16, 256), blk, 0, stream>>>(ow[3], WBhi, WBlo);
        conv_mfma<16, 7, 25, 25, 19, 19, 98, 7, 4, 25><<<dim3(CEILDIV(Mv, 256), 2), blk, 0, stream>>>(PL4h, PL4l, WBhi, WBlo, ob[3], OFF, Mv);
        wprep_d<16, 49, 52, 16, 16><<<CEILDIV(2 * 52 * 16 * 8, 256), blk, 0, stream>>>(w[3], WDhi, WDlo);
        deform_mfma<7, 16, 16, 25, 25, 19, 19, true, 8, 52, true><<<dim3(B * 3), dim3(512), 0, stream>>>(PL4h, PL4l, OFF, WDhi, WDlo, bi[3], nullptr, PL5h, PL5l);
    }
    // ---- stage 5: CI=16 K=5 19x19->15x15 OC(off)=50 CO=8. PL5 -> Q (fp32 NCHW) ----
    {
        const int Mv = B * 225;
        wprep<16, 25, 26, 64, 50><<<CEILDIV(26 * 64 * 16, 256), blk, 0, stream>>>(ow[4], WBhi, WBlo);
        conv_mfma<16, 5, 19, 19, 15, 15, 50, 4, 4, 13><<<dim3(CEILDIV(Mv, 256), 1), blk, 0, stream>>>(PL5h, PL5l, WBhi, WBlo, ob[4], OFF, Mv);
        wprep_d<16, 25, 28, 16, 8><<<CEILDIV(2 * 28 * 16 * 8, 256), blk, 0, stream>>>(w[4], WDhi, WDlo);
        deform_mfma<5, 16, 8, 19, 19, 15, 15, true, 4, 28, false><<<dim3(B * 4), dim3(256), 0, stream>>>(PL5h, PL5l, OFF, WDhi, WDlo, bi[4], Q, nullptr, nullptr);
    }
    // ---- stage 6: CI=8 K=3 15x15->13x13 CO=4. Q -> P (fp32 NCHW) ----
    conv_tile<3, 8, 6, 18, 15, 15, 13, 13, 4><<<GRIDT(13, 13, 4, 3), blk, 0, stream>>>(Q, ow[5], ob[5], OFF);
    deform_lds<3, 8, 4, 15, 15, 13, 13, true, 8, 12, 192, 1, false><<<dim3(B), dim3(192), 0, stream>>>(Q, OFF, w[5], bi[5], P, nullptr, nullptr);

    // ---- FC head (reads P = 512 x 4 x 13 x 13) ----
    wtrans<676, 256><<<CEILDIV(676 * 256, 256), blk, 0, stream>>>(fc1w, WT1);
    wtrans<256, 10><<<CEILDIV(256 * 10, 256), blk, 0, stream>>>(fc2w, WT2);
    fc_t<676, 256, true><<<dim3(CEILDIV(B * 256, 256)), blk, 0, stream>>>(P, WT1, fc1b, Z, B);
    fc_t<256, 10, false><<<dim3(CEILDIV(B * 10, 256)), blk, 0, stream>>>(Z, WT2, fc2b, out, B);

    #undef GRIDT
    #undef CEILDIV
}

// Round 7
// 839.483 us; speedup vs baseline: 1.3523x; 1.3523x over previous
//
#include <hip/hip_runtime.h>

typedef __attribute__((ext_vector_type(8))) short bf16x8;
typedef __attribute__((ext_vector_type(4))) float f32x4;
typedef __attribute__((ext_vector_type(2))) float f32x2;
typedef __attribute__((ext_vector_type(4))) unsigned int u32x4;
typedef unsigned short ushort_t;

__device__ inline ushort_t bf16_trunc(float f) { return (ushort_t)(__float_as_uint(f) >> 16); }
__device__ inline float bf16_to_f(ushort_t u) { return __uint_as_float(((unsigned int)u) << 16); }

// packed fp32 (CDNA3+): two IEEE fp32 ops per instruction
__device__ inline f32x2 pk_mul(f32x2 a, f32x2 b) {
    f32x2 d;
    asm("v_pk_mul_f32 %0, %1, %2" : "=v"(d) : "v"(a), "v"(b));
    return d;
}
__device__ inline f32x2 pk_fma(f32x2 a, f32x2 b, f32x2 c) {
    f32x2 d;
    asm("v_pk_fma_f32 %0, %1, %2, %3" : "=v"(d) : "v"(a), "v"(b), "v"(c));
    return d;
}

// pack top-16-bits of two fp32 into one u32: (u0>>16) | (u1 & 0xffff0000)
__device__ inline unsigned int hi_pair(unsigned int u1, unsigned int u0) {
    return __builtin_amdgcn_perm(u1, u0, 0x07060302u);
}

// split 8 fp32 (sA,sB) into bf16 hi + bf16 lo fragments via v_perm packing
__device__ inline void split8(const f32x4 sA, const f32x4 sB, bf16x8& ahi, bf16x8& alo)
{
    unsigned int u[8], h[8], d[8];
#pragma unroll
    for (int j = 0; j < 4; ++j) {
        u[j]     = __float_as_uint(sA[j]);
        u[4 + j] = __float_as_uint(sB[j]);
    }
#pragma unroll
    for (int j = 0; j < 8; ++j) {
        h[j] = u[j] & 0xffff0000u;                       // exact bf16-hi as f32 bits
        d[j] = __float_as_uint(__uint_as_float(u[j]) - __uint_as_float(h[j]));
    }
    union { u32x4 w; bf16x8 v; } H, L;
    H.w = (u32x4){hi_pair(h[1], h[0]), hi_pair(h[3], h[2]), hi_pair(h[5], h[4]), hi_pair(h[7], h[6])};
    L.w = (u32x4){hi_pair(d[1], d[0]), hi_pair(d[3], d[2]), hi_pair(d[5], d[4]), hi_pair(d[7], d[6])};
    ahi = H.v;
    alo = L.v;
}

// ---------------------------------------------------------------------------
// Weight prep for conv_mfma: OIHW fp32 -> [kk][n][ci] hi/lo, zero-padded.
// ---------------------------------------------------------------------------
template<int CI, int KK, int KKPAD, int NPAD, int OC>
__global__ __launch_bounds__(256)
void wprep(const float* __restrict__ w, ushort_t* __restrict__ bhi, ushort_t* __restrict__ blo)
{
    const int idx = blockIdx.x * 256 + threadIdx.x;
    if (idx >= KKPAD * NPAD * CI) return;
    const int kk  = idx / (NPAD * CI);
    const int rem = idx - kk * (NPAD * CI);
    const int n   = rem / CI;
    const int ci  = rem - n * CI;
    const float v = (kk < KK && n < OC) ? w[((size_t)n * CI + ci) * KK + kk] : 0.f;
    const ushort_t h = bf16_trunc(v);
    bhi[idx] = h;
    blo[idx] = bf16_trunc(v - bf16_to_f(h));
}

// ---------------------------------------------------------------------------
// Weight prep for deform_mfma: pack [kslot = g8*TPAD+tap][n][j=ci_in_group].
// ---------------------------------------------------------------------------
template<int CI, int KK, int TPAD, int NPAD, int OC>
__global__ __launch_bounds__(256)
void wprep_d(const float* __restrict__ w, ushort_t* __restrict__ bhi, ushort_t* __restrict__ blo)
{
    constexpr int NPASS = (CI + 7) / 8;
    constexpr int TOTAL = NPASS * TPAD * NPAD * 8;
    const int idx = blockIdx.x * 256 + threadIdx.x;
    if (idx >= TOTAL) return;
    const int j     = idx & 7;
    const int n     = (idx >> 3) % NPAD;
    const int kslot = (idx >> 3) / NPAD;
    const int pass  = kslot / TPAD;
    const int tap   = kslot - pass * TPAD;
    const int ci    = pass * 8 + j;
    const float v = (tap < KK && n < OC && ci < CI) ? w[((size_t)n * CI + ci) * KK + tap] : 0.f;
    const ushort_t h = bf16_trunc(v);
    bhi[idx] = h;
    blo[idx] = bf16_trunc(v - bf16_to_f(h));
}

// ---------------------------------------------------------------------------
// MFMA implicit-im2col conv, v7: barrier-free + DOUBLE-BUFFERED REGISTER
// PREFETCH FOR BOTH A AND B.
//  [r6 lesson] barrier-free with just-in-time B loads exposed L2 latency
//  every K-step (MfmaUtil 15%). Fix = same pattern that fixed A in r3:
//  issue step ks+1's A AND B global loads before step ks's MFMA phase.
//  The compiler's waitcnt before consuming buffer pb leaves buffer pb^1's
//  16 loads in flight across the whole MFMA phase (~240+ cyc >= L2 lat).
//  Still no LDS, no __syncthreads: waves free-run.
// ---------------------------------------------------------------------------
template<int CI, int K, int H, int W, int Ho, int Wo, int OC, int NTTOT, int NT0, int KSTEPS>
__global__ __launch_bounds__(256)
void conv_mfma(const ushort_t* __restrict__ Xhi, const ushort_t* __restrict__ Xlo,
               const ushort_t* __restrict__ Bhi, const ushort_t* __restrict__ Blo,
               const float* __restrict__ bias, float* __restrict__ out, int Mtotal)
{
    constexpr int NPAD = NTTOT * 16;
    constexpr int HW   = H * W;
    constexpr int HoWo = Ho * Wo;
    constexpr int NPASS = CI / 8;

    const int tid  = threadIdx.x;
    const int lane = tid & 63;
    const int wid  = tid >> 6;
    const int col  = lane & 15;
    const int quad = lane >> 4;

    const int mBase  = blockIdx.x * 256 + wid * 64;
    const int ntBase = blockIdx.y * NT0;

    int aBase[4];
#pragma unroll
    for (int mt = 0; mt < 4; ++mt) {
        int mm = mBase + mt * 16 + col;
        if (mm >= Mtotal) mm = Mtotal - 1;
        const int b   = mm / HoWo;
        const int pos = mm - b * HoWo;
        const int oy  = pos / Wo;
        const int ox  = pos - oy * Wo;
        aBase[mt] = b * NPASS * HW + oy * W + ox;
    }

    f32x4 acc[4][NT0];
#pragma unroll
    for (int mt = 0; mt < 4; ++mt)
#pragma unroll
        for (int nt = 0; nt < NT0; ++nt) acc[mt][nt] = (f32x4){0.f, 0.f, 0.f, 0.f};

    // double-buffered A and B fragments (prefetched one K-step ahead)
    bf16x8 ah[2][4], al[2][4];
    bf16x8 bh[2][NT0], bl[2][NT0];

    auto loadA = [&](int ks, int pb) {
        const int k0   = ks * 32 + quad * 8;
        const int tap  = k0 / CI;
        const int ci   = k0 - tap * CI;
        const int g    = ci >> 3;
        const int dkk  = (tap / K) * W + (tap - (tap / K) * K);
#pragma unroll
        for (int mt = 0; mt < 4; ++mt) {
            const size_t aoff = (size_t)(aBase[mt] + g * HW + dkk) * 8;
            ah[pb][mt] = *(const bf16x8*)(Xhi + aoff);
            al[pb][mt] = *(const bf16x8*)(Xlo + aoff);
        }
    };

    auto loadB = [&](int ks, int pb) {
        const int k0   = ks * 32 + quad * 8;
        const int tap  = k0 / CI;
        const int ci   = k0 - tap * CI;
#pragma unroll
        for (int nt = 0; nt < NT0; ++nt) {
            int ntg = ntBase + nt;
            if (ntg > NTTOT - 1) ntg = NTTOT - 1;       // clamp: stay in-bounds
            const size_t boff = ((size_t)tap * NPAD + ntg * 16 + col) * CI + ci;
            bh[pb][nt] = *(const bf16x8*)(Bhi + boff);
            bl[pb][nt] = *(const bf16x8*)(Blo + boff);
        }
    };

    loadA(0, 0);
    loadB(0, 0);

#pragma unroll
    for (int ks = 0; ks < KSTEPS; ++ks) {
        const int pb = ks & 1;
        if (ks + 1 < KSTEPS) {
            loadA(ks + 1, pb ^ 1);        // in flight across the MFMA phase below
            loadB(ks + 1, pb ^ 1);
        }

#pragma unroll
        for (int nt = 0; nt < NT0; ++nt) {
            const int ntg = ntBase + nt;
            if (ntg < NTTOT) {
#pragma unroll
                for (int mt = 0; mt < 4; ++mt) {
                    acc[mt][nt] = __builtin_amdgcn_mfma_f32_16x16x32_bf16(ah[pb][mt], bh[pb][nt], acc[mt][nt], 0, 0, 0);
                    acc[mt][nt] = __builtin_amdgcn_mfma_f32_16x16x32_bf16(al[pb][mt], bh[pb][nt], acc[mt][nt], 0, 0, 0);
                    acc[mt][nt] = __builtin_amdgcn_mfma_f32_16x16x32_bf16(ah[pb][mt], bl[pb][nt], acc[mt][nt], 0, 0, 0);
                }
            }
        }
    }

#pragma unroll
    for (int mt = 0; mt < 4; ++mt) {
#pragma unroll
        for (int nt = 0; nt < NT0; ++nt) {
            const int ntg = ntBase + nt;
            const int n   = ntg * 16 + col;
            if (ntg < NTTOT && n < OC) {
                const float bv = bias[n];
#pragma unroll
                for (int r = 0; r < 4; ++r) {
                    const int m = mBase + mt * 16 + quad * 4 + r;
                    if (m < Mtotal) {
                        const int b   = m / HoWo;
                        const int pos = m - b * HoWo;
                        out[((size_t)b * OC + n) * HoWo + pos] = acc[mt][nt][r] + bv;
                    }
                }
            }
        }
    }
}

// ---------------------------------------------------------------------------
// MFMA deformable conv (stages 2-5), v6: single-pass staging + packed-fp32
// interp + dead-wave skip. [r5 measured: TLP-bound on LDS gather — model
// 122 µs vs 131.6 measured @ stage 3; at its structural floor.]
// ---------------------------------------------------------------------------
template<int K, int CI, int CO, int H, int W, int Ho, int Wo, bool RELU,
         int MT, int TPAD, bool OUTPL>
__global__ __launch_bounds__(MT * 64, 4)
void deform_mfma(const ushort_t* __restrict__ Xhi, const ushort_t* __restrict__ Xlo,
                 const float* __restrict__ off,
                 const ushort_t* __restrict__ Bph, const ushort_t* __restrict__ Bpl,
                 const float* __restrict__ bias,
                 float* __restrict__ outF, ushort_t* __restrict__ oHi, ushort_t* __restrict__ oLo)
{
    static_assert(CI % 8 == 0, "channel-grouped layout requires CI % 8 == 0");
    constexpr int KK     = K * K;
    constexpr int HW     = H * W;
    constexpr int HoWo   = Ho * Wo;
    constexpr int GP     = CI / 8;          // 8-channel groups, all staged at once
    constexpr int NPO    = CO / 8;
    constexpr int NT     = (CO + 15) / 16;
    constexpr int NPAD   = NT * 16;
    constexpr int TSTR   = CI + 4;          // floats per position (mult of 4)
    constexpr int TG     = TPAD / 4;
    constexpr int nMB    = (HoWo + MT * 16 - 1) / (MT * 16);
    constexpr int THREADS = MT * 64;
    __shared__ __align__(16) float tile[HW * TSTR];

    const int b    = blockIdx.x / nMB;
    const int mb   = blockIdx.x - b * nMB;
    const int tid  = threadIdx.x;
    const int wid  = tid >> 6;
    const int lane = tid & 63;
    const int col  = lane & 15;
    const int quad = lane >> 4;

    const int pixel0 = (mb * MT + wid) * 16;
    const int s      = pixel0 + col;
    const bool am    = (s < HoWo);
    const int oy = s / Wo, ox = s - oy * Wo;

    const float* offB = off + (size_t)b * 2 * KK * HoWo;

    f32x4 acc[NT];
#pragma unroll
    for (int nt = 0; nt < NT; ++nt) acc[nt] = (f32x4){0.f, 0.f, 0.f, 0.f};

    // ---- stage the full CI-channel input image into LDS (one pass) ----
    for (int pos = tid; pos < HW; pos += THREADS) {
        float* tp = tile + pos * TSTR;
#pragma unroll
        for (int g = 0; g < GP; ++g) {
            const size_t gbase = ((size_t)(b * GP + g) * HW + pos) * 8;
            const bf16x8 h8 = *(const bf16x8*)(Xhi + gbase);
            const bf16x8 l8 = *(const bf16x8*)(Xlo + gbase);
            f32x4 vA, vB;
#pragma unroll
            for (int j = 0; j < 4; ++j) {
                vA[j] = bf16_to_f((ushort_t)h8[j])     + bf16_to_f((ushort_t)l8[j]);
                vB[j] = bf16_to_f((ushort_t)h8[4 + j]) + bf16_to_f((ushort_t)l8[4 + j]);
            }
            *(f32x4*)(tp + g * 8)     = vA;
            *(f32x4*)(tp + g * 8 + 4) = vB;
        }
    }
    __syncthreads();

    if (pixel0 < HoWo) {      // dead-wave skip (wave-uniform; no barrier below)
#pragma unroll
        for (int tg = 0; tg < TG; ++tg) {
            const int tap = tg * 4 + quad;

            float w00 = 0.f, w01 = 0.f, w10 = 0.f, w11 = 0.f;
            int   i00 = 0,   i01 = 0,   i10 = 0,   i11 = 0;

            if (am && tap < KK) {
                const float dy = offB[(size_t)(2 * tap + 0) * HoWo + s];
                const float dx = offB[(size_t)(2 * tap + 1) * HoWo + s];
                const float py = (float)(tap / K + oy) + dy;
                const float px = (float)(tap % K + ox) + dx;
                const float y0f = floorf(py), x0f = floorf(px);
                const float wy = py - y0f, wx = px - x0f;
                const int y0 = (int)y0f, x0 = (int)x0f;
                const int y1 = y0 + 1,   x1 = x0 + 1;

                const float m00 = (y0 >= 0 && y0 < H && x0 >= 0 && x0 < W) ? 1.f : 0.f;
                const float m01 = (y0 >= 0 && y0 < H && x1 >= 0 && x1 < W) ? 1.f : 0.f;
                const float m10 = (y1 >= 0 && y1 < H && x0 >= 0 && x0 < W) ? 1.f : 0.f;
                const float m11 = (y1 >= 0 && y1 < H && x1 >= 0 && x1 < W) ? 1.f : 0.f;

                w00 = (1.f - wy) * (1.f - wx) * m00;
                w01 = (1.f - wy) * wx         * m01;
                w10 = wy         * (1.f - wx) * m10;
                w11 = wy         * wx         * m11;

                const int y0c = min(max(y0, 0), H - 1), y1c = min(max(y1, 0), H - 1);
                const int x0c = min(max(x0, 0), W - 1), x1c = min(max(x1, 0), W - 1);
                i00 = (y0c * W + x0c) * TSTR;
                i01 = (y0c * W + x1c) * TSTR;
                i10 = (y1c * W + x0c) * TSTR;
                i11 = (y1c * W + x1c) * TSTR;
            }

            const f32x2 w00p = {w00, w00}, w01p = {w01, w01};
            const f32x2 w10p = {w10, w10}, w11p = {w11, w11};

#pragma unroll
            for (int g = 0; g < GP; ++g) {
                const float* tp = tile + g * 8;
                const f32x4 a00 = *(const f32x4*)(tp + i00);
                const f32x4 c00 = *(const f32x4*)(tp + i00 + 4);
                const f32x4 a01 = *(const f32x4*)(tp + i01);
                const f32x4 c01 = *(const f32x4*)(tp + i01 + 4);
                const f32x4 a10 = *(const f32x4*)(tp + i10);
                const f32x4 c10 = *(const f32x4*)(tp + i10 + 4);
                const f32x4 a11 = *(const f32x4*)(tp + i11);
                const f32x4 c11 = *(const f32x4*)(tp + i11 + 4);

#define LOH(v) __builtin_shufflevector(v, v, 0, 1)
#define HIH(v) __builtin_shufflevector(v, v, 2, 3)
                f32x2 sA0 = pk_mul(LOH(a00), w00p);
                sA0 = pk_fma(LOH(a01), w01p, sA0);
                sA0 = pk_fma(LOH(a10), w10p, sA0);
                sA0 = pk_fma(LOH(a11), w11p, sA0);
                f32x2 sA1 = pk_mul(HIH(a00), w00p);
                sA1 = pk_fma(HIH(a01), w01p, sA1);
                sA1 = pk_fma(HIH(a10), w10p, sA1);
                sA1 = pk_fma(HIH(a11), w11p, sA1);
                f32x2 sB0 = pk_mul(LOH(c00), w00p);
                sB0 = pk_fma(LOH(c01), w01p, sB0);
                sB0 = pk_fma(LOH(c10), w10p, sB0);
                sB0 = pk_fma(LOH(c11), w11p, sB0);
                f32x2 sB1 = pk_mul(HIH(c00), w00p);
                sB1 = pk_fma(HIH(c01), w01p, sB1);
                sB1 = pk_fma(HIH(c10), w10p, sB1);
                sB1 = pk_fma(HIH(c11), w11p, sB1);
#undef LOH
#undef HIH
                const f32x4 sA = __builtin_shufflevector(sA0, sA1, 0, 1, 2, 3);
                const f32x4 sB = __builtin_shufflevector(sB0, sB1, 0, 1, 2, 3);

                bf16x8 ahi, alo;
                split8(sA, sB, ahi, alo);

                const int kslot = g * TPAD + tap;
#pragma unroll
                for (int nt = 0; nt < NT; ++nt) {
                    const bf16x8 bh = *(const bf16x8*)(Bph + ((size_t)kslot * NPAD + nt * 16 + col) * 8);
                    const bf16x8 bl = *(const bf16x8*)(Bpl + ((size_t)kslot * NPAD + nt * 16 + col) * 8);
                    acc[nt] = __builtin_amdgcn_mfma_f32_16x16x32_bf16(ahi, bh, acc[nt], 0, 0, 0);
                    acc[nt] = __builtin_amdgcn_mfma_f32_16x16x32_bf16(alo, bh, acc[nt], 0, 0, 0);
                    acc[nt] = __builtin_amdgcn_mfma_f32_16x16x32_bf16(ahi, bl, acc[nt], 0, 0, 0);
                }
            }
        }
    }

#pragma unroll
    for (int nt = 0; nt < NT; ++nt) {
        const int n = nt * 16 + col;
        if (n < CO) {
            const float bv = bias[n];
#pragma unroll
            for (int r = 0; r < 4; ++r) {
                const int m = pixel0 + quad * 4 + r;
                if (m < HoWo) {
                    float v = acc[nt][r] + bv;
                    if (RELU) v = fmaxf(v, 0.f);
                    if (OUTPL) {
                        const size_t o = (((size_t)b * NPO + (n >> 3)) * HoWo + m) * 8 + (n & 7);
                        const ushort_t h = bf16_trunc(v);
                        oHi[o] = h;
                        oLo[o] = bf16_trunc(v - bf16_to_f(h));
                    } else {
                        outF[((size_t)b * CO + n) * HoWo + m] = v;
                    }
                }
            }
        }
    }
}

// ---------------------------------------------------------------------------
// Scalar LDS deform (stages 1 and 6). Reads fp32 NCHW. Epilogue writes
// grouped planes (OUTPL, stage 1) or fp32 NCHW (stage 6).
// ---------------------------------------------------------------------------
template<int K, int CI, int CO, int H, int W, int Ho, int Wo, bool RELU,
         int CSPLIT, int STRIDE, int THREADS, int SPLIT, bool OUTPL>
__global__ __launch_bounds__(THREADS)
void deform_lds(const float* __restrict__ x, const float* __restrict__ off,
                const float* __restrict__ w, const float* __restrict__ bias,
                float* __restrict__ outF, ushort_t* __restrict__ oHi, ushort_t* __restrict__ oLo)
{
    constexpr int KK    = K * K;
    constexpr int HW    = H * W;
    constexpr int HoWo  = Ho * Wo;
    constexpr int NPASS = CI / CSPLIT;
    constexpr int NPO   = (CO + 7) / 8;
    constexpr int CHUNK = (HoWo + SPLIT - 1) / SPLIT;
    static_assert(CHUNK <= THREADS, "chunk must fit in one block");
    __shared__ __align__(16) float tile[HW * STRIDE];

    const int b   = blockIdx.x / SPLIT;
    const int sp  = blockIdx.x - b * SPLIT;
    const int tid = threadIdx.x;
    const int s   = sp * CHUNK + tid;
    const bool active = (tid < CHUNK) && (s < HoWo);

    const int oy = s / Wo, ox = s - oy * Wo;
    const float* offp = off + ((size_t)b * 2 * KK) * HoWo + s;

    float acc[CO];
#pragma unroll
    for (int o = 0; o < CO; ++o) acc[o] = 0.f;

    for (int pass = 0; pass < NPASS; ++pass) {
        const int cbase = pass * CSPLIT;
        __syncthreads();
        for (int pos = tid; pos < HW; pos += THREADS) {
#pragma unroll
            for (int c = 0; c < CSPLIT; ++c)
                tile[pos * STRIDE + c] = x[((size_t)b * CI + (cbase + c)) * HW + pos];
        }
        __syncthreads();

        if (active) {
            for (int kk = 0; kk < KK; ++kk) {
                const float dy = offp[(size_t)(2 * kk + 0) * HoWo];
                const float dx = offp[(size_t)(2 * kk + 1) * HoWo];
                const float py = (float)(kk / K + oy) + dy;
                const float px = (float)(kk % K + ox) + dx;
                const float y0f = floorf(py), x0f = floorf(px);
                const float wy = py - y0f, wx = px - x0f;
                const int y0 = (int)y0f, x0 = (int)x0f;
                const int y1 = y0 + 1,   x1 = x0 + 1;

                const float m00 = (y0 >= 0 && y0 < H && x0 >= 0 && x0 < W) ? 1.f : 0.f;
                const float m01 = (y0 >= 0 && y0 < H && x1 >= 0 && x1 < W) ? 1.f : 0.f;
                const float m10 = (y1 >= 0 && y1 < H && x0 >= 0 && x0 < W) ? 1.f : 0.f;
                const float m11 = (y1 >= 0 && y1 < H && x1 >= 0 && x1 < W) ? 1.f : 0.f;

                const float w00 = (1.f - wy) * (1.f - wx) * m00;
                const float w01 = (1.f - wy) * wx         * m01;
                const float w10 = wy         * (1.f - wx) * m10;
                const float w11 = wy         * wx         * m11;

                const int y0c = min(max(y0, 0), H - 1), y1c = min(max(y1, 0), H - 1);
                const int x0c = min(max(x0, 0), W - 1), x1c = min(max(x1, 0), W - 1);
                const int i00 = (y0c * W + x0c) * STRIDE;
                const int i01 = (y0c * W + x1c) * STRIDE;
                const int i10 = (y1c * W + x0c) * STRIDE;
                const int i11 = (y1c * W + x1c) * STRIDE;

                if constexpr (CSPLIT % 4 == 0) {
#pragma unroll
                    for (int cg = 0; cg < CSPLIT; cg += 4) {
                        const f32x4 v00 = *(const f32x4*)(tile + i00 + cg);
                        const f32x4 v01 = *(const f32x4*)(tile + i01 + cg);
                        const f32x4 v10 = *(const f32x4*)(tile + i10 + cg);
                        const f32x4 v11 = *(const f32x4*)(tile + i11 + cg);
#pragma unroll
                        for (int j = 0; j < 4; ++j) {
                            const float sv = fmaf(v11[j], w11, fmaf(v10[j], w10,
                                             fmaf(v01[j], w01, v00[j] * w00)));
#pragma unroll
                            for (int o = 0; o < CO; ++o)
                                acc[o] = fmaf(sv, w[(size_t)(o * CI + cbase + cg + j) * KK + kk], acc[o]);
                        }
                    }
                } else {
                    const float sv = fmaf(tile[i11], w11, fmaf(tile[i10], w10,
                                     fmaf(tile[i01], w01, tile[i00] * w00)));
#pragma unroll
                    for (int o = 0; o < CO; ++o)
                        acc[o] = fmaf(sv, w[(size_t)(o * CI + cbase) * KK + kk], acc[o]);
                }
            }
        }
    }

    if (active) {
#pragma unroll
        for (int o = 0; o < CO; ++o) {
            float v = acc[o] + bias[o];
            if (RELU) v = fmaxf(v, 0.f);
            if (OUTPL) {
                const size_t oi = (((size_t)b * NPO + (o >> 3)) * HoWo + s) * 8 + (o & 7);
                const ushort_t h = bf16_trunc(v);
                oHi[oi] = h;
                oLo[oi] = bf16_trunc(v - bf16_to_f(h));
            } else {
                outF[((size_t)b * CO + o) * HoWo + s] = v;
            }
        }
    }
}

// ---------------------------------------------------------------------------
// Register-tiled direct VALID conv (stages 1 and 6 offset convs).
// ---------------------------------------------------------------------------
template<int K, int CI, int NOC, int OC, int H, int W, int Ho, int Wo, int PIX>
__global__ __launch_bounds__(256)
void conv_tile(const float* __restrict__ x, const float* __restrict__ w,
               const float* __restrict__ bias, float* __restrict__ out)
{
    constexpr int KK   = K * K;
    constexpr int HoWo = Ho * Wo;
    constexpr int WoG  = (Wo + PIX - 1) / PIX;
    constexpr int G    = Ho * WoG;
    constexpr int XV   = PIX + K - 1;

    const int oc0   = blockIdx.y * NOC;
    const int g_all = blockIdx.x * 256 + threadIdx.x;
    const int b     = g_all / G;
    const int g     = g_all - b * G;
    const int oy    = g / WoG;
    const int ox0   = (g - oy * WoG) * PIX;

    const float* xbp = x + (b * CI) * (H * W) + oy * W + ox0;
    const float* wp  = w + oc0 * (CI * KK);

    float acc[PIX][NOC];
#pragma unroll
    for (int p = 0; p < PIX; ++p)
#pragma unroll
        for (int j = 0; j < NOC; ++j) acc[p][j] = bias[oc0 + j];

    const int lim = W - 1 - ox0;

    for (int ci = 0; ci < CI; ++ci) {
        const float* xc = xbp + ci * (H * W);
#pragma unroll
        for (int ky = 0; ky < K; ++ky) {
            float xv[XV];
#pragma unroll
            for (int i = 0; i < XV; ++i) {
                const int off = (i <= lim) ? i : lim;
                xv[i] = xc[ky * W + off];
            }
#pragma unroll
            for (int kx = 0; kx < K; ++kx) {
#pragma unroll
                for (int p = 0; p < PIX; ++p) {
                    const float v = xv[p + kx];
#pragma unroll
                    for (int j = 0; j < NOC; ++j)
                        acc[p][j] = fmaf(v, wp[j * (CI * KK) + ci * KK + ky * K + kx], acc[p][j]);
                }
            }
        }
    }

    float* op = out + (b * OC + oc0) * HoWo + oy * Wo + ox0;
#pragma unroll
    for (int p = 0; p < PIX; ++p) {
        if (ox0 + p < Wo) {
#pragma unroll
            for (int j = 0; j < NOC; ++j) op[j * HoWo + p] = acc[p][j];
        }
    }
}

// ---------------------------------------------------------------------------
// FC weight transpose + coalesced FC.
// ---------------------------------------------------------------------------
template<int IN, int OUT>
__global__ __launch_bounds__(256)
void wtrans(const float* __restrict__ w, float* __restrict__ wt)
{
    const int idx = blockIdx.x * 256 + threadIdx.x;
    if (idx >= IN * OUT) return;
    const int i = idx / OUT, j = idx - i * OUT;
    wt[idx] = w[(size_t)j * IN + i];
}

template<int IN, int OUT, bool RELU>
__global__ __launch_bounds__(256)
void fc_t(const float* __restrict__ h, const float* __restrict__ wt,
          const float* __restrict__ bias, float* __restrict__ out, int B)
{
    const int idx = blockIdx.x * 256 + threadIdx.x;
    if (idx >= B * OUT) return;
    const int b = idx / OUT;
    const int j = idx - b * OUT;
    const float* hb = h + (size_t)b * IN;
    float acc = bias[j];
#pragma unroll 4
    for (int i = 0; i < IN; ++i)
        acc = fmaf(hb[i], wt[(size_t)i * OUT + j], acc);
    if (RELU) acc = fmaxf(acc, 0.f);
    out[idx] = acc;
}

// ---------------------------------------------------------------------------
extern "C" void kernel_launch(void* const* d_in, const int* in_sizes, int n_in,
                              void* d_out, int out_size, void* d_ws, size_t ws_size,
                              hipStream_t stream)
{
    const int B = 512;
    const float* x = (const float*)d_in[0];
    const float *ow[6], *ob[6], *w[6], *bi[6];
    for (int i = 0; i < 6; ++i) {
        ow[i] = (const float*)d_in[1 + 4 * i];
        ob[i] = (const float*)d_in[2 + 4 * i];
        w[i]  = (const float*)d_in[3 + 4 * i];
        bi[i] = (const float*)d_in[4 + 4 * i];
    }
    const float* fc1w = (const float*)d_in[25];
    const float* fc1b = (const float*)d_in[26];
    const float* fc2w = (const float*)d_in[27];
    const float* fc2b = (const float*)d_in[28];
    float* out = (float*)d_out;

    float* P   = (float*)d_ws;        // 14M floats
    float* Q   = P  + 14000000;       // 14M floats
    float* OFF = Q  + 14000000;       // 18.2M floats
    float* Z   = OFF + 18200000;      // fc intermediate
    ushort_t* WBhi = (ushort_t*)(Z + 200000);
    ushort_t* WBlo = WBhi + 200000;
    ushort_t* WDhi = WBlo + 200000;
    ushort_t* WDlo = WDhi + 200000;
    float* WT1 = (float*)(WDlo + 200000);
    float* WT2 = WT1 + 173056;

    const dim3 blk(256);
    #define GRIDT(Ho, Wo, PIX, NG) dim3((B * (Ho) * (((Wo) + (PIX) - 1) / (PIX)) + 255) / 256, (NG), 1)
    #define CEILDIV(a, b) (((a) + (b) - 1) / (b))

    // plane regions (channel-grouped layout)
    ushort_t* PL2h = (ushort_t*)Q;  ushort_t* PL2l = PL2h + (size_t)(B * 961 + 2048) * 16;
    ushort_t* PL3h = (ushort_t*)P;  ushort_t* PL3l = PL3h + (size_t)(B * 841 + 2048) * 32;
    ushort_t* PL4h = (ushort_t*)Q;  ushort_t* PL4l = PL4h + (size_t)(B * 625 + 2048) * 16;
    ushort_t* PL5h = (ushort_t*)P;  ushort_t* PL5l = PL5h + (size_t)(B * 361 + 2048) * 16;

    // ---- stage 1: input x (CI=1). conv_tile -> OFF; deform_lds -> PL2 ----
    conv_tile<3, 1, 6, 18, 33, 33, 31, 31, 4><<<GRIDT(31, 31, 4, 3), blk, 0, stream>>>(x, ow[0], ob[0], OFF);
    deform_lds<3, 1, 16, 33, 33, 31, 31, true, 1, 1, 512, 2, true><<<dim3(B * 2), dim3(512), 0, stream>>>(x, OFF, w[0], bi[0], nullptr, PL2h, PL2l);

    // ---- stage 2: CI=16 K=3 31x31->29x29 OC(off)=18 CO=32. PL2 -> PL3 ----
    {
        const int Mv = B * 841;
        wprep<16, 9, 10, 32, 18><<<CEILDIV(10 * 32 * 16, 256), blk, 0, stream>>>(ow[1], WBhi, WBlo);
        conv_mfma<16, 3, 31, 31, 29, 29, 18, 2, 2, 5><<<dim3(CEILDIV(Mv, 256), 1), blk, 0, stream>>>(PL2h, PL2l, WBhi, WBlo, ob[1], OFF, Mv);
        wprep_d<16, 9, 12, 32, 32><<<CEILDIV(2 * 12 * 32 * 8, 256), blk, 0, stream>>>(w[1], WDhi, WDlo);
        deform_mfma<3, 16, 32, 31, 31, 29, 29, true, 8, 12, true><<<dim3(B * 7), dim3(512), 0, stream>>>(PL2h, PL2l, OFF, WDhi, WDlo, bi[1], nullptr, PL3h, PL3l);
    }
    // ---- stage 3: CI=32 K=5 29x29->25x25 OC(off)=50 CO=16 (no relu). PL3 -> PL4 ----
    {
        const int Mv = B * 625;
        wprep<32, 25, 25, 64, 50><<<CEILDIV(25 * 64 * 32, 256), blk, 0, stream>>>(ow[2], WBhi, WBlo);
        conv_mfma<32, 5, 29, 29, 25, 25, 50, 4, 4, 25><<<dim3(CEILDIV(Mv, 256), 1), blk, 0, stream>>>(PL3h, PL3l, WBhi, WBlo, ob[2], OFF, Mv);
        wprep_d<32, 25, 28, 16, 16><<<CEILDIV(4 * 28 * 16 * 8, 256), blk, 0, stream>>>(w[2], WDhi, WDlo);
        deform_mfma<5, 32, 16, 29, 29, 25, 25, false, 14, 28, true><<<dim3(B * 3), dim3(896), 0, stream>>>(PL3h, PL3l, OFF, WDhi, WDlo, bi[2], nullptr, PL4h, PL4l);
    }
    // ---- stage 4: CI=16 K=7 25x25->19x19 OC(off)=98 CO=16. PL4 -> PL5 ----
    {
        const int Mv = B * 361;
        wprep<16, 49, 50, 112, 98><<<CEILDIV(50 * 112 * 16, 256), blk, 0, stream>>>(ow[3], WBhi, WBlo);
        conv_mfma<16, 7, 25, 25, 19, 19, 98, 7, 4, 25><<<dim3(CEILDIV(Mv, 256), 2), blk, 0, stream>>>(PL4h, PL4l, WBhi, WBlo, ob[3], OFF, Mv);
        wprep_d<16, 49, 52, 16, 16><<<CEILDIV(2 * 52 * 16 * 8, 256), blk, 0, stream>>>(w[3], WDhi, WDlo);
        deform_mfma<7, 16, 16, 25, 25, 19, 19, true, 8, 52, true><<<dim3(B * 3), dim3(512), 0, stream>>>(PL4h, PL4l, OFF, WDhi, WDlo, bi[3], nullptr, PL5h, PL5l);
    }
    // ---- stage 5: CI=16 K=5 19x19->15x15 OC(off)=50 CO=8. PL5 -> Q (fp32 NCHW) ----
    {
        const int Mv = B * 225;
        wprep<16, 25, 26, 64, 50><<<CEILDIV(26 * 64 * 16, 256), blk, 0, stream>>>(ow[4], WBhi, WBlo);
        conv_mfma<16, 5, 19, 19, 15, 15, 50, 4, 4, 13><<<dim3(CEILDIV(Mv, 256), 1), blk, 0, stream>>>(PL5h, PL5l, WBhi, WBlo, ob[4], OFF, Mv);
        wprep_d<16, 25, 28, 16, 8><<<CEILDIV(2 * 28 * 16 * 8, 256), blk, 0, stream>>>(w[4], WDhi, WDlo);
        deform_mfma<5, 16, 8, 19, 19, 15, 15, true, 4, 28, false><<<dim3(B * 4), dim3(256), 0, stream>>>(PL5h, PL5l, OFF, WDhi, WDlo, bi[4], Q, nullptr, nullptr);
    }
    // ---- stage 6: CI=8 K=3 15x15->13x13 CO=4. Q -> P (fp32 NCHW) ----
    conv_tile<3, 8, 6, 18, 15, 15, 13, 13, 4><<<GRIDT(13, 13, 4, 3), blk, 0, stream>>>(Q, ow[5], ob[5], OFF);
    deform_lds<3, 8, 4, 15, 15, 13, 13, true, 8, 12, 192, 1, false><<<dim3(B), dim3(192), 0, stream>>>(Q, OFF, w[5], bi[5], P, nullptr, nullptr);

    // ---- FC head (reads P = 512 x 4 x 13 x 13) ----
    wtrans<676, 256><<<CEILDIV(676 * 256, 256), blk, 0, stream>>>(fc1w, WT1);
    wtrans<256, 10><<<CEILDIV(256 * 10, 256), blk, 0, stream>>>(fc2w, WT2);
    fc_t<676, 256, true><<<dim3(CEILDIV(B * 256, 256)), blk, 0, stream>>>(P, WT1, fc1b, Z, B);
    fc_t<256, 10, false><<<dim3(CEILDIV(B * 10, 256)), blk, 0, stream>>>(Z, WT2, fc2b, out, B);

    #undef GRIDT
    #undef CEILDIV
}

// Round 8
// 819.117 us; speedup vs baseline: 1.3859x; 1.0249x over previous
//
#include <hip/hip_runtime.h>

typedef __attribute__((ext_vector_type(8))) short bf16x8;
typedef __attribute__((ext_vector_type(4))) float f32x4;
typedef __attribute__((ext_vector_type(2))) float f32x2;
typedef __attribute__((ext_vector_type(4))) unsigned int u32x4;
typedef unsigned short ushort_t;

__device__ inline ushort_t bf16_trunc(float f) { return (ushort_t)(__float_as_uint(f) >> 16); }
__device__ inline float bf16_to_f(ushort_t u) { return __uint_as_float(((unsigned int)u) << 16); }

// LDS-publish barrier WITHOUT vmcnt drain (HK/8-phase pattern, T3/T4):
// waits only lgkmcnt(0) (this wave's ds_write publish + ds_read completion)
// then raw s_barrier. Wave-private global prefetch loads stay IN FLIGHT
// across the barrier — the compiler's own counted vmcnt before their first
// use provides correctness. sched_barrier(0) pins ordering (guide rule #18).
__device__ inline void lds_barrier() {
    __builtin_amdgcn_sched_barrier(0);
    asm volatile("s_waitcnt lgkmcnt(0)" ::: "memory");
    __builtin_amdgcn_s_barrier();
    __builtin_amdgcn_sched_barrier(0);
}

// packed fp32 (CDNA3+): two IEEE fp32 ops per instruction
__device__ inline f32x2 pk_mul(f32x2 a, f32x2 b) {
    f32x2 d;
    asm("v_pk_mul_f32 %0, %1, %2" : "=v"(d) : "v"(a), "v"(b));
    return d;
}
__device__ inline f32x2 pk_fma(f32x2 a, f32x2 b, f32x2 c) {
    f32x2 d;
    asm("v_pk_fma_f32 %0, %1, %2, %3" : "=v"(d) : "v"(a), "v"(b), "v"(c));
    return d;
}

// pack top-16-bits of two fp32 into one u32: (u0>>16) | (u1 & 0xffff0000)
__device__ inline unsigned int hi_pair(unsigned int u1, unsigned int u0) {
    return __builtin_amdgcn_perm(u1, u0, 0x07060302u);
}

// split 8 fp32 (sA,sB) into bf16 hi + bf16 lo fragments via v_perm packing
__device__ inline void split8(const f32x4 sA, const f32x4 sB, bf16x8& ahi, bf16x8& alo)
{
    unsigned int u[8], h[8], d[8];
#pragma unroll
    for (int j = 0; j < 4; ++j) {
        u[j]     = __float_as_uint(sA[j]);
        u[4 + j] = __float_as_uint(sB[j]);
    }
#pragma unroll
    for (int j = 0; j < 8; ++j) {
        h[j] = u[j] & 0xffff0000u;                       // exact bf16-hi as f32 bits
        d[j] = __float_as_uint(__uint_as_float(u[j]) - __uint_as_float(h[j]));
    }
    union { u32x4 w; bf16x8 v; } H, L;
    H.w = (u32x4){hi_pair(h[1], h[0]), hi_pair(h[3], h[2]), hi_pair(h[5], h[4]), hi_pair(h[7], h[6])};
    L.w = (u32x4){hi_pair(d[1], d[0]), hi_pair(d[3], d[2]), hi_pair(d[5], d[4]), hi_pair(d[7], d[6])};
    ahi = H.v;
    alo = L.v;
}

// ---------------------------------------------------------------------------
// Weight prep for conv_mfma: OIHW fp32 -> [kk][n][ci] hi/lo, zero-padded.
// ---------------------------------------------------------------------------
template<int CI, int KK, int KKPAD, int NPAD, int OC>
__global__ __launch_bounds__(256)
void wprep(const float* __restrict__ w, ushort_t* __restrict__ bhi, ushort_t* __restrict__ blo)
{
    const int idx = blockIdx.x * 256 + threadIdx.x;
    if (idx >= KKPAD * NPAD * CI) return;
    const int kk  = idx / (NPAD * CI);
    const int rem = idx - kk * (NPAD * CI);
    const int n   = rem / CI;
    const int ci  = rem - n * CI;
    const float v = (kk < KK && n < OC) ? w[((size_t)n * CI + ci) * KK + kk] : 0.f;
    const ushort_t h = bf16_trunc(v);
    bhi[idx] = h;
    blo[idx] = bf16_trunc(v - bf16_to_f(h));
}

// ---------------------------------------------------------------------------
// Weight prep for deform_mfma: pack [kslot = g8*TPAD+tap][n][j=ci_in_group].
// ---------------------------------------------------------------------------
template<int CI, int KK, int TPAD, int NPAD, int OC>
__global__ __launch_bounds__(256)
void wprep_d(const float* __restrict__ w, ushort_t* __restrict__ bhi, ushort_t* __restrict__ blo)
{
    constexpr int NPASS = (CI + 7) / 8;
    constexpr int TOTAL = NPASS * TPAD * NPAD * 8;
    const int idx = blockIdx.x * 256 + threadIdx.x;
    if (idx >= TOTAL) return;
    const int j     = idx & 7;
    const int n     = (idx >> 3) % NPAD;
    const int kslot = (idx >> 3) / NPAD;
    const int pass  = kslot / TPAD;
    const int tap   = kslot - pass * TPAD;
    const int ci    = pass * 8 + j;
    const float v = (tap < KK && n < OC && ci < CI) ? w[((size_t)n * CI + ci) * KK + tap] : 0.f;
    const ushort_t h = bf16_trunc(v);
    bhi[idx] = h;
    blo[idx] = bf16_trunc(v - bf16_to_f(h));
}

// ---------------------------------------------------------------------------
// MFMA implicit-im2col conv, v8: r3's LDS B-slab + A-register prefetch, with
// the per-K-step __syncthreads replaced by lds_barrier() (lgkmcnt-only drain).
//  [r7 lesson] reg-only A+B: 116+64acc = 180 unified regs -> 2 waves/SIMD,
//  MfmaUtil 28.5%. LDS slab keeps VGPR at ~80+64 -> 3 waves/SIMD.
//  [r3 flaw fixed] __syncthreads' vmcnt(0) drained the A prefetch every
//  step, capping cover at ~233 cyc < L3 latency. lds_barrier keeps the A
//  loads in flight across barriers; only LDS state is published.
// ---------------------------------------------------------------------------
template<int CI, int K, int H, int W, int Ho, int Wo, int OC, int NTTOT, int NT0, int KSTEPS>
__global__ __launch_bounds__(256)
void conv_mfma(const ushort_t* __restrict__ Xhi, const ushort_t* __restrict__ Xlo,
               const ushort_t* __restrict__ Bhi, const ushort_t* __restrict__ Blo,
               const float* __restrict__ bias, float* __restrict__ out, int Mtotal)
{
    constexpr int NPAD = NTTOT * 16;
    constexpr int HW   = H * W;
    constexpr int HoWo = Ho * Wo;
    constexpr int NPASS = CI / 8;
    constexpr int TKS  = 32 / CI;
    constexpr int ROWS = TKS * NT0 * 16;
    constexpr int BSTR = CI + 8;
    constexpr int CH8  = CI / 8;
    constexpr int CHUNKS = ROWS * CH8;

    __shared__ __align__(16) ushort_t sBh[2][ROWS * BSTR];
    __shared__ __align__(16) ushort_t sBl[2][ROWS * BSTR];

    const int tid  = threadIdx.x;
    const int lane = tid & 63;
    const int wid  = tid >> 6;
    const int col  = lane & 15;
    const int quad = lane >> 4;

    const int mBase  = blockIdx.x * 256 + wid * 64;
    const int ntBase = blockIdx.y * NT0;

    int aBase[4];
#pragma unroll
    for (int mt = 0; mt < 4; ++mt) {
        int mm = mBase + mt * 16 + col;
        if (mm >= Mtotal) mm = Mtotal - 1;
        const int b   = mm / HoWo;
        const int pos = mm - b * HoWo;
        const int oy  = pos / Wo;
        const int ox  = pos - oy * Wo;
        aBase[mt] = b * NPASS * HW + oy * W + ox;
    }

    f32x4 acc[4][NT0];
#pragma unroll
    for (int mt = 0; mt < 4; ++mt)
#pragma unroll
        for (int nt = 0; nt < NT0; ++nt) acc[mt][nt] = (f32x4){0.f, 0.f, 0.f, 0.f};

    auto loadSlab = [&](int ks, int buf) {
        const int tap0 = ks * TKS;
        for (int i = tid; i < CHUNKS; i += 256) {
            const int row = i / CH8;
            const int c8  = i - row * CH8;
            const int t   = row / (NT0 * 16);
            const int nn  = row - t * (NT0 * 16);
            int n = ntBase * 16 + nn;
            if (n > NPAD - 1) n = NPAD - 1;
            const int g = ((tap0 + t) * NPAD + n) * CI + c8 * 8;
            *(bf16x8*)(sBh[buf] + row * BSTR + c8 * 8) = *(const bf16x8*)(Bhi + g);
            *(bf16x8*)(sBl[buf] + row * BSTR + c8 * 8) = *(const bf16x8*)(Blo + g);
        }
    };

    // double-buffered A fragments (prefetched one K-step ahead; loads stay
    // in flight across lds_barrier — no vmcnt drain)
    bf16x8 ah[2][4], al[2][4];

    auto loadA = [&](int ks, int pb) {
        const int k0   = ks * 32 + quad * 8;
        const int tap  = k0 / CI;
        const int ci   = k0 - tap * CI;
        const int g    = ci >> 3;
        const int dkk  = (tap / K) * W + (tap - (tap / K) * K);
#pragma unroll
        for (int mt = 0; mt < 4; ++mt) {
            const size_t aoff = (size_t)(aBase[mt] + g * HW + dkk) * 8;
            ah[pb][mt] = *(const bf16x8*)(Xhi + aoff);
            al[pb][mt] = *(const bf16x8*)(Xlo + aoff);
        }
    };

    loadA(0, 0);
    loadSlab(0, 0);
    lds_barrier();

#pragma unroll
    for (int ks = 0; ks < KSTEPS; ++ks) {
        if (ks + 1 < KSTEPS) {
            loadA(ks + 1, (ks + 1) & 1);      // prefetch: floats across barrier
            loadSlab(ks + 1, (ks + 1) & 1);
        }

        const int k0   = ks * 32 + quad * 8;
        const int tap  = k0 / CI;
        const int tloc = tap - ks * TKS;
        const int ci   = k0 - tap * CI;
        const int pb   = ks & 1;

        const ushort_t* __restrict__ bhp = sBh[pb];
        const ushort_t* __restrict__ blp = sBl[pb];
#pragma unroll
        for (int nt = 0; nt < NT0; ++nt) {
            const int ntg = ntBase + nt;
            if (ntg < NTTOT) {
                const int lrow = ((tloc * NT0 + nt) * 16 + col) * BSTR + ci;
                const bf16x8 bh = *(const bf16x8*)(bhp + lrow);
                const bf16x8 bl = *(const bf16x8*)(blp + lrow);
#pragma unroll
                for (int mt = 0; mt < 4; ++mt) {
                    acc[mt][nt] = __builtin_amdgcn_mfma_f32_16x16x32_bf16(ah[pb][mt], bh, acc[mt][nt], 0, 0, 0);
                    acc[mt][nt] = __builtin_amdgcn_mfma_f32_16x16x32_bf16(al[pb][mt], bh, acc[mt][nt], 0, 0, 0);
                    acc[mt][nt] = __builtin_amdgcn_mfma_f32_16x16x32_bf16(ah[pb][mt], bl, acc[mt][nt], 0, 0, 0);
                }
            }
        }
        lds_barrier();
    }

#pragma unroll
    for (int mt = 0; mt < 4; ++mt) {
#pragma unroll
        for (int nt = 0; nt < NT0; ++nt) {
            const int ntg = ntBase + nt;
            const int n   = ntg * 16 + col;
            if (ntg < NTTOT && n < OC) {
                const float bv = bias[n];
#pragma unroll
                for (int r = 0; r < 4; ++r) {
                    const int m = mBase + mt * 16 + quad * 4 + r;
                    if (m < Mtotal) {
                        const int b   = m / HoWo;
                        const int pos = m - b * HoWo;
                        out[((size_t)b * OC + n) * HoWo + pos] = acc[mt][nt][r] + bv;
                    }
                }
            }
        }
    }
}

// ---------------------------------------------------------------------------
// MFMA deformable conv (stages 2-5), v6: single-pass staging + packed-fp32
// interp + dead-wave skip. [r5 measured: TLP-bound on LDS gather — model
// 122 µs vs 131.6 measured @ stage 3; at its structural floor.]
// ---------------------------------------------------------------------------
template<int K, int CI, int CO, int H, int W, int Ho, int Wo, bool RELU,
         int MT, int TPAD, bool OUTPL>
__global__ __launch_bounds__(MT * 64, 4)
void deform_mfma(const ushort_t* __restrict__ Xhi, const ushort_t* __restrict__ Xlo,
                 const float* __restrict__ off,
                 const ushort_t* __restrict__ Bph, const ushort_t* __restrict__ Bpl,
                 const float* __restrict__ bias,
                 float* __restrict__ outF, ushort_t* __restrict__ oHi, ushort_t* __restrict__ oLo)
{
    static_assert(CI % 8 == 0, "channel-grouped layout requires CI % 8 == 0");
    constexpr int KK     = K * K;
    constexpr int HW     = H * W;
    constexpr int HoWo   = Ho * Wo;
    constexpr int GP     = CI / 8;          // 8-channel groups, all staged at once
    constexpr int NPO    = CO / 8;
    constexpr int NT     = (CO + 15) / 16;
    constexpr int NPAD   = NT * 16;
    constexpr int TSTR   = CI + 4;          // floats per position (mult of 4)
    constexpr int TG     = TPAD / 4;
    constexpr int nMB    = (HoWo + MT * 16 - 1) / (MT * 16);
    constexpr int THREADS = MT * 64;
    __shared__ __align__(16) float tile[HW * TSTR];

    const int b    = blockIdx.x / nMB;
    const int mb   = blockIdx.x - b * nMB;
    const int tid  = threadIdx.x;
    const int wid  = tid >> 6;
    const int lane = tid & 63;
    const int col  = lane & 15;
    const int quad = lane >> 4;

    const int pixel0 = (mb * MT + wid) * 16;
    const int s      = pixel0 + col;
    const bool am    = (s < HoWo);
    const int oy = s / Wo, ox = s - oy * Wo;

    const float* offB = off + (size_t)b * 2 * KK * HoWo;

    f32x4 acc[NT];
#pragma unroll
    for (int nt = 0; nt < NT; ++nt) acc[nt] = (f32x4){0.f, 0.f, 0.f, 0.f};

    // ---- stage the full CI-channel input image into LDS (one pass) ----
    for (int pos = tid; pos < HW; pos += THREADS) {
        float* tp = tile + pos * TSTR;
#pragma unroll
        for (int g = 0; g < GP; ++g) {
            const size_t gbase = ((size_t)(b * GP + g) * HW + pos) * 8;
            const bf16x8 h8 = *(const bf16x8*)(Xhi + gbase);
            const bf16x8 l8 = *(const bf16x8*)(Xlo + gbase);
            f32x4 vA, vB;
#pragma unroll
            for (int j = 0; j < 4; ++j) {
                vA[j] = bf16_to_f((ushort_t)h8[j])     + bf16_to_f((ushort_t)l8[j]);
                vB[j] = bf16_to_f((ushort_t)h8[4 + j]) + bf16_to_f((ushort_t)l8[4 + j]);
            }
            *(f32x4*)(tp + g * 8)     = vA;
            *(f32x4*)(tp + g * 8 + 4) = vB;
        }
    }
    __syncthreads();

    if (pixel0 < HoWo) {      // dead-wave skip (wave-uniform; no barrier below)
#pragma unroll
        for (int tg = 0; tg < TG; ++tg) {
            const int tap = tg * 4 + quad;

            float w00 = 0.f, w01 = 0.f, w10 = 0.f, w11 = 0.f;
            int   i00 = 0,   i01 = 0,   i10 = 0,   i11 = 0;

            if (am && tap < KK) {
                const float dy = offB[(size_t)(2 * tap + 0) * HoWo + s];
                const float dx = offB[(size_t)(2 * tap + 1) * HoWo + s];
                const float py = (float)(tap / K + oy) + dy;
                const float px = (float)(tap % K + ox) + dx;
                const float y0f = floorf(py), x0f = floorf(px);
                const float wy = py - y0f, wx = px - x0f;
                const int y0 = (int)y0f, x0 = (int)x0f;
                const int y1 = y0 + 1,   x1 = x0 + 1;

                const float m00 = (y0 >= 0 && y0 < H && x0 >= 0 && x0 < W) ? 1.f : 0.f;
                const float m01 = (y0 >= 0 && y0 < H && x1 >= 0 && x1 < W) ? 1.f : 0.f;
                const float m10 = (y1 >= 0 && y1 < H && x0 >= 0 && x0 < W) ? 1.f : 0.f;
                const float m11 = (y1 >= 0 && y1 < H && x1 >= 0 && x1 < W) ? 1.f : 0.f;

                w00 = (1.f - wy) * (1.f - wx) * m00;
                w01 = (1.f - wy) * wx         * m01;
                w10 = wy         * (1.f - wx) * m10;
                w11 = wy         * wx         * m11;

                const int y0c = min(max(y0, 0), H - 1), y1c = min(max(y1, 0), H - 1);
                const int x0c = min(max(x0, 0), W - 1), x1c = min(max(x1, 0), W - 1);
                i00 = (y0c * W + x0c) * TSTR;
                i01 = (y0c * W + x1c) * TSTR;
                i10 = (y1c * W + x0c) * TSTR;
                i11 = (y1c * W + x1c) * TSTR;
            }

            const f32x2 w00p = {w00, w00}, w01p = {w01, w01};
            const f32x2 w10p = {w10, w10}, w11p = {w11, w11};

#pragma unroll
            for (int g = 0; g < GP; ++g) {
                const float* tp = tile + g * 8;
                const f32x4 a00 = *(const f32x4*)(tp + i00);
                const f32x4 c00 = *(const f32x4*)(tp + i00 + 4);
                const f32x4 a01 = *(const f32x4*)(tp + i01);
                const f32x4 c01 = *(const f32x4*)(tp + i01 + 4);
                const f32x4 a10 = *(const f32x4*)(tp + i10);
                const f32x4 c10 = *(const f32x4*)(tp + i10 + 4);
                const f32x4 a11 = *(const f32x4*)(tp + i11);
                const f32x4 c11 = *(const f32x4*)(tp + i11 + 4);

#define LOH(v) __builtin_shufflevector(v, v, 0, 1)
#define HIH(v) __builtin_shufflevector(v, v, 2, 3)
                f32x2 sA0 = pk_mul(LOH(a00), w00p);
                sA0 = pk_fma(LOH(a01), w01p, sA0);
                sA0 = pk_fma(LOH(a10), w10p, sA0);
                sA0 = pk_fma(LOH(a11), w11p, sA0);
                f32x2 sA1 = pk_mul(HIH(a00), w00p);
                sA1 = pk_fma(HIH(a01), w01p, sA1);
                sA1 = pk_fma(HIH(a10), w10p, sA1);
                sA1 = pk_fma(HIH(a11), w11p, sA1);
                f32x2 sB0 = pk_mul(LOH(c00), w00p);
                sB0 = pk_fma(LOH(c01), w01p, sB0);
                sB0 = pk_fma(LOH(c10), w10p, sB0);
                sB0 = pk_fma(LOH(c11), w11p, sB0);
                f32x2 sB1 = pk_mul(HIH(c00), w00p);
                sB1 = pk_fma(HIH(c01), w01p, sB1);
                sB1 = pk_fma(HIH(c10), w10p, sB1);
                sB1 = pk_fma(HIH(c11), w11p, sB1);
#undef LOH
#undef HIH
                const f32x4 sA = __builtin_shufflevector(sA0, sA1, 0, 1, 2, 3);
                const f32x4 sB = __builtin_shufflevector(sB0, sB1, 0, 1, 2, 3);

                bf16x8 ahi, alo;
                split8(sA, sB, ahi, alo);

                const int kslot = g * TPAD + tap;
#pragma unroll
                for (int nt = 0; nt < NT; ++nt) {
                    const bf16x8 bh = *(const bf16x8*)(Bph + ((size_t)kslot * NPAD + nt * 16 + col) * 8);
                    const bf16x8 bl = *(const bf16x8*)(Bpl + ((size_t)kslot * NPAD + nt * 16 + col) * 8);
                    acc[nt] = __builtin_amdgcn_mfma_f32_16x16x32_bf16(ahi, bh, acc[nt], 0, 0, 0);
                    acc[nt] = __builtin_amdgcn_mfma_f32_16x16x32_bf16(alo, bh, acc[nt], 0, 0, 0);
                    acc[nt] = __builtin_amdgcn_mfma_f32_16x16x32_bf16(ahi, bl, acc[nt], 0, 0, 0);
                }
            }
        }
    }

#pragma unroll
    for (int nt = 0; nt < NT; ++nt) {
        const int n = nt * 16 + col;
        if (n < CO) {
            const float bv = bias[n];
#pragma unroll
            for (int r = 0; r < 4; ++r) {
                const int m = pixel0 + quad * 4 + r;
                if (m < HoWo) {
                    float v = acc[nt][r] + bv;
                    if (RELU) v = fmaxf(v, 0.f);
                    if (OUTPL) {
                        const size_t o = (((size_t)b * NPO + (n >> 3)) * HoWo + m) * 8 + (n & 7);
                        const ushort_t h = bf16_trunc(v);
                        oHi[o] = h;
                        oLo[o] = bf16_trunc(v - bf16_to_f(h));
                    } else {
                        outF[((size_t)b * CO + n) * HoWo + m] = v;
                    }
                }
            }
        }
    }
}

// ---------------------------------------------------------------------------
// Scalar LDS deform (stages 1 and 6). Reads fp32 NCHW. Epilogue writes
// grouped planes (OUTPL, stage 1) or fp32 NCHW (stage 6).
// ---------------------------------------------------------------------------
template<int K, int CI, int CO, int H, int W, int Ho, int Wo, bool RELU,
         int CSPLIT, int STRIDE, int THREADS, int SPLIT, bool OUTPL>
__global__ __launch_bounds__(THREADS)
void deform_lds(const float* __restrict__ x, const float* __restrict__ off,
                const float* __restrict__ w, const float* __restrict__ bias,
                float* __restrict__ outF, ushort_t* __restrict__ oHi, ushort_t* __restrict__ oLo)
{
    constexpr int KK    = K * K;
    constexpr int HW    = H * W;
    constexpr int HoWo  = Ho * Wo;
    constexpr int NPASS = CI / CSPLIT;
    constexpr int NPO   = (CO + 7) / 8;
    constexpr int CHUNK = (HoWo + SPLIT - 1) / SPLIT;
    static_assert(CHUNK <= THREADS, "chunk must fit in one block");
    __shared__ __align__(16) float tile[HW * STRIDE];

    const int b   = blockIdx.x / SPLIT;
    const int sp  = blockIdx.x - b * SPLIT;
    const int tid = threadIdx.x;
    const int s   = sp * CHUNK + tid;
    const bool active = (tid < CHUNK) && (s < HoWo);

    const int oy = s / Wo, ox = s - oy * Wo;
    const float* offp = off + ((size_t)b * 2 * KK) * HoWo + s;

    float acc[CO];
#pragma unroll
    for (int o = 0; o < CO; ++o) acc[o] = 0.f;

    for (int pass = 0; pass < NPASS; ++pass) {
        const int cbase = pass * CSPLIT;
        __syncthreads();
        for (int pos = tid; pos < HW; pos += THREADS) {
#pragma unroll
            for (int c = 0; c < CSPLIT; ++c)
                tile[pos * STRIDE + c] = x[((size_t)b * CI + (cbase + c)) * HW + pos];
        }
        __syncthreads();

        if (active) {
            for (int kk = 0; kk < KK; ++kk) {
                const float dy = offp[(size_t)(2 * kk + 0) * HoWo];
                const float dx = offp[(size_t)(2 * kk + 1) * HoWo];
                const float py = (float)(kk / K + oy) + dy;
                const float px = (float)(kk % K + ox) + dx;
                const float y0f = floorf(py), x0f = floorf(px);
                const float wy = py - y0f, wx = px - x0f;
                const int y0 = (int)y0f, x0 = (int)x0f;
                const int y1 = y0 + 1,   x1 = x0 + 1;

                const float m00 = (y0 >= 0 && y0 < H && x0 >= 0 && x0 < W) ? 1.f : 0.f;
                const float m01 = (y0 >= 0 && y0 < H && x1 >= 0 && x1 < W) ? 1.f : 0.f;
                const float m10 = (y1 >= 0 && y1 < H && x0 >= 0 && x0 < W) ? 1.f : 0.f;
                const float m11 = (y1 >= 0 && y1 < H && x1 >= 0 && x1 < W) ? 1.f : 0.f;

                const float w00 = (1.f - wy) * (1.f - wx) * m00;
                const float w01 = (1.f - wy) * wx         * m01;
                const float w10 = wy         * (1.f - wx) * m10;
                const float w11 = wy         * wx         * m11;

                const int y0c = min(max(y0, 0), H - 1), y1c = min(max(y1, 0), H - 1);
                const int x0c = min(max(x0, 0), W - 1), x1c = min(max(x1, 0), W - 1);
                const int i00 = (y0c * W + x0c) * STRIDE;
                const int i01 = (y0c * W + x1c) * STRIDE;
                const int i10 = (y1c * W + x0c) * STRIDE;
                const int i11 = (y1c * W + x1c) * STRIDE;

                if constexpr (CSPLIT % 4 == 0) {
#pragma unroll
                    for (int cg = 0; cg < CSPLIT; cg += 4) {
                        const f32x4 v00 = *(const f32x4*)(tile + i00 + cg);
                        const f32x4 v01 = *(const f32x4*)(tile + i01 + cg);
                        const f32x4 v10 = *(const f32x4*)(tile + i10 + cg);
                        const f32x4 v11 = *(const f32x4*)(tile + i11 + cg);
#pragma unroll
                        for (int j = 0; j < 4; ++j) {
                            const float sv = fmaf(v11[j], w11, fmaf(v10[j], w10,
                                             fmaf(v01[j], w01, v00[j] * w00)));
#pragma unroll
                            for (int o = 0; o < CO; ++o)
                                acc[o] = fmaf(sv, w[(size_t)(o * CI + cbase + cg + j) * KK + kk], acc[o]);
                        }
                    }
                } else {
                    const float sv = fmaf(tile[i11], w11, fmaf(tile[i10], w10,
                                     fmaf(tile[i01], w01, tile[i00] * w00)));
#pragma unroll
                    for (int o = 0; o < CO; ++o)
                        acc[o] = fmaf(sv, w[(size_t)(o * CI + cbase) * KK + kk], acc[o]);
                }
            }
        }
    }

    if (active) {
#pragma unroll
        for (int o = 0; o < CO; ++o) {
            float v = acc[o] + bias[o];
            if (RELU) v = fmaxf(v, 0.f);
            if (OUTPL) {
                const size_t oi = (((size_t)b * NPO + (o >> 3)) * HoWo + s) * 8 + (o & 7);
                const ushort_t h = bf16_trunc(v);
                oHi[oi] = h;
                oLo[oi] = bf16_trunc(v - bf16_to_f(h));
            } else {
                outF[((size_t)b * CO + o) * HoWo + s] = v;
            }
        }
    }
}

// ---------------------------------------------------------------------------
// Register-tiled direct VALID conv (stages 1 and 6 offset convs).
// ---------------------------------------------------------------------------
template<int K, int CI, int NOC, int OC, int H, int W, int Ho, int Wo, int PIX>
__global__ __launch_bounds__(256)
void conv_tile(const float* __restrict__ x, const float* __restrict__ w,
               const float* __restrict__ bias, float* __restrict__ out)
{
    constexpr int KK   = K * K;
    constexpr int HoWo = Ho * Wo;
    constexpr int WoG  = (Wo + PIX - 1) / PIX;
    constexpr int G    = Ho * WoG;
    constexpr int XV   = PIX + K - 1;

    const int oc0   = blockIdx.y * NOC;
    const int g_all = blockIdx.x * 256 + threadIdx.x;
    const int b     = g_all / G;
    const int g     = g_all - b * G;
    const int oy    = g / WoG;
    const int ox0   = (g - oy * WoG) * PIX;

    const float* xbp = x + (b * CI) * (H * W) + oy * W + ox0;
    const float* wp  = w + oc0 * (CI * KK);

    float acc[PIX][NOC];
#pragma unroll
    for (int p = 0; p < PIX; ++p)
#pragma unroll
        for (int j = 0; j < NOC; ++j) acc[p][j] = bias[oc0 + j];

    const int lim = W - 1 - ox0;

    for (int ci = 0; ci < CI; ++ci) {
        const float* xc = xbp + ci * (H * W);
#pragma unroll
        for (int ky = 0; ky < K; ++ky) {
            float xv[XV];
#pragma unroll
            for (int i = 0; i < XV; ++i) {
                const int off = (i <= lim) ? i : lim;
                xv[i] = xc[ky * W + off];
            }
#pragma unroll
            for (int kx = 0; kx < K; ++kx) {
#pragma unroll
                for (int p = 0; p < PIX; ++p) {
                    const float v = xv[p + kx];
#pragma unroll
                    for (int j = 0; j < NOC; ++j)
                        acc[p][j] = fmaf(v, wp[j * (CI * KK) + ci * KK + ky * K + kx], acc[p][j]);
                }
            }
        }
    }

    float* op = out + (b * OC + oc0) * HoWo + oy * Wo + ox0;
#pragma unroll
    for (int p = 0; p < PIX; ++p) {
        if (ox0 + p < Wo) {
#pragma unroll
            for (int j = 0; j < NOC; ++j) op[j * HoWo + p] = acc[p][j];
        }
    }
}

// ---------------------------------------------------------------------------
// FC weight transpose + coalesced FC.
// ---------------------------------------------------------------------------
template<int IN, int OUT>
__global__ __launch_bounds__(256)
void wtrans(const float* __restrict__ w, float* __restrict__ wt)
{
    const int idx = blockIdx.x * 256 + threadIdx.x;
    if (idx >= IN * OUT) return;
    const int i = idx / OUT, j = idx - i * OUT;
    wt[idx] = w[(size_t)j * IN + i];
}

template<int IN, int OUT, bool RELU>
__global__ __launch_bounds__(256)
void fc_t(const float* __restrict__ h, const float* __restrict__ wt,
          const float* __restrict__ bias, float* __restrict__ out, int B)
{
    const int idx = blockIdx.x * 256 + threadIdx.x;
    if (idx >= B * OUT) return;
    const int b = idx / OUT;
    const int j = idx - b * OUT;
    const float* hb = h + (size_t)b * IN;
    float acc = bias[j];
#pragma unroll 4
    for (int i = 0; i < IN; ++i)
        acc = fmaf(hb[i], wt[(size_t)i * OUT + j], acc);
    if (RELU) acc = fmaxf(acc, 0.f);
    out[idx] = acc;
}

// ---------------------------------------------------------------------------
extern "C" void kernel_launch(void* const* d_in, const int* in_sizes, int n_in,
                              void* d_out, int out_size, void* d_ws, size_t ws_size,
                              hipStream_t stream)
{
    const int B = 512;
    const float* x = (const float*)d_in[0];
    const float *ow[6], *ob[6], *w[6], *bi[6];
    for (int i = 0; i < 6; ++i) {
        ow[i] = (const float*)d_in[1 + 4 * i];
        ob[i] = (const float*)d_in[2 + 4 * i];
        w[i]  = (const float*)d_in[3 + 4 * i];
        bi[i] = (const float*)d_in[4 + 4 * i];
    }
    const float* fc1w = (const float*)d_in[25];
    const float* fc1b = (const float*)d_in[26];
    const float* fc2w = (const float*)d_in[27];
    const float* fc2b = (const float*)d_in[28];
    float* out = (float*)d_out;

    float* P   = (float*)d_ws;        // 14M floats
    float* Q   = P  + 14000000;       // 14M floats
    float* OFF = Q  + 14000000;       // 18.2M floats
    float* Z   = OFF + 18200000;      // fc intermediate
    ushort_t* WBhi = (ushort_t*)(Z + 200000);
    ushort_t* WBlo = WBhi + 200000;
    ushort_t* WDhi = WBlo + 200000;
    ushort_t* WDlo = WDhi + 200000;
    float* WT1 = (float*)(WDlo + 200000);
    float* WT2 = WT1 + 173056;

    const dim3 blk(256);
    #define GRIDT(Ho, Wo, PIX, NG) dim3((B * (Ho) * (((Wo) + (PIX) - 1) / (PIX)) + 255) / 256, (NG), 1)
    #define CEILDIV(a, b) (((a) + (b) - 1) / (b))

    // plane regions (channel-grouped layout)
    ushort_t* PL2h = (ushort_t*)Q;  ushort_t* PL2l = PL2h + (size_t)(B * 961 + 2048) * 16;
    ushort_t* PL3h = (ushort_t*)P;  ushort_t* PL3l = PL3h + (size_t)(B * 841 + 2048) * 32;
    ushort_t* PL4h = (ushort_t*)Q;  ushort_t* PL4l = PL4h + (size_t)(B * 625 + 2048) * 16;
    ushort_t* PL5h = (ushort_t*)P;  ushort_t* PL5l = PL5h + (size_t)(B * 361 + 2048) * 16;

    // ---- stage 1: input x (CI=1). conv_tile -> OFF; deform_lds -> PL2 ----
    conv_tile<3, 1, 6, 18, 33, 33, 31, 31, 4><<<GRIDT(31, 31, 4, 3), blk, 0, stream>>>(x, ow[0], ob[0], OFF);
    deform_lds<3, 1, 16, 33, 33, 31, 31, true, 1, 1, 512, 2, true><<<dim3(B * 2), dim3(512), 0, stream>>>(x, OFF, w[0], bi[0], nullptr, PL2h, PL2l);

    // ---- stage 2: CI=16 K=3 31x31->29x29 OC(off)=18 CO=32. PL2 -> PL3 ----
    {
        const int Mv = B * 841;
        wprep<16, 9, 10, 32, 18><<<CEILDIV(10 * 32 * 16, 256), blk, 0, stream>>>(ow[1], WBhi, WBlo);
        conv_mfma<16, 3, 31, 31, 29, 29, 18, 2, 2, 5><<<dim3(CEILDIV(Mv, 256), 1), blk, 0, stream>>>(PL2h, PL2l, WBhi, WBlo, ob[1], OFF, Mv);
        wprep_d<16, 9, 12, 32, 32><<<CEILDIV(2 * 12 * 32 * 8, 256), blk, 0, stream>>>(w[1], WDhi, WDlo);
        deform_mfma<3, 16, 32, 31, 31, 29, 29, true, 8, 12, true><<<dim3(B * 7), dim3(512), 0, stream>>>(PL2h, PL2l, OFF, WDhi, WDlo, bi[1], nullptr, PL3h, PL3l);
    }
    // ---- stage 3: CI=32 K=5 29x29->25x25 OC(off)=50 CO=16 (no relu). PL3 -> PL4 ----
    {
        const int Mv = B * 625;
        wprep<32, 25, 25, 64, 50><<<CEILDIV(25 * 64 * 32, 256), blk, 0, stream>>>(ow[2], WBhi, WBlo);
        conv_mfma<32, 5, 29, 29, 25, 25, 50, 4, 4, 25><<<dim3(CEILDIV(Mv, 256), 1), blk, 0, stream>>>(PL3h, PL3l, WBhi, WBlo, ob[2], OFF, Mv);
        wprep_d<32, 25, 28, 16, 16><<<CEILDIV(4 * 28 * 16 * 8, 256), blk, 0, stream>>>(w[2], WDhi, WDlo);
        deform_mfma<5, 32, 16, 29, 29, 25, 25, false, 14, 28, true><<<dim3(B * 3), dim3(896), 0, stream>>>(PL3h, PL3l, OFF, WDhi, WDlo, bi[2], nullptr, PL4h, PL4l);
    }
    // ---- stage 4: CI=16 K=7 25x25->19x19 OC(off)=98 CO=16. PL4 -> PL5 ----
    {
        const int Mv = B * 361;
        wprep<16, 49, 50, 112, 98><<<CEILDIV(50 * 112 * 16, 256), blk, 0, stream>>>(ow[3], WBhi, WBlo);
        conv_mfma<16, 7, 25, 25, 19, 19, 98, 7, 4, 25><<<dim3(CEILDIV(Mv, 256), 2), blk, 0, stream>>>(PL4h, PL4l, WBhi, WBlo, ob[3], OFF, Mv);
        wprep_d<16, 49, 52, 16, 16><<<CEILDIV(2 * 52 * 16 * 8, 256), blk, 0, stream>>>(w[3], WDhi, WDlo);
        deform_mfma<7, 16, 16, 25, 25, 19, 19, true, 8, 52, true><<<dim3(B * 3), dim3(512), 0, stream>>>(PL4h, PL4l, OFF, WDhi, WDlo, bi[3], nullptr, PL5h, PL5l);
    }
    // ---- stage 5: CI=16 K=5 19x19->15x15 OC(off)=50 CO=8. PL5 -> Q (fp32 NCHW) ----
    {
        const int Mv = B * 225;
        wprep<16, 25, 26, 64, 50><<<CEILDIV(26 * 64 * 16, 256), blk, 0, stream>>>(ow[4], WBhi, WBlo);
        conv_mfma<16, 5, 19, 19, 15, 15, 50, 4, 4, 13><<<dim3(CEILDIV(Mv, 256), 1), blk, 0, stream>>>(PL5h, PL5l, WBhi, WBlo, ob[4], OFF, Mv);
        wprep_d<16, 25, 28, 16, 8><<<CEILDIV(2 * 28 * 16 * 8, 256), blk, 0, stream>>>(w[4], WDhi, WDlo);
        deform_mfma<5, 16, 8, 19, 19, 15, 15, true, 4, 28, false><<<dim3(B * 4), dim3(256), 0, stream>>>(PL5h, PL5l, OFF, WDhi, WDlo, bi[4], Q, nullptr, nullptr);
    }
    // ---- stage 6: CI=8 K=3 15x15->13x13 CO=4. Q -> P (fp32 NCHW) ----
    conv_tile<3, 8, 6, 18, 15, 15, 13, 13, 4><<<GRIDT(13, 13, 4, 3), blk, 0, stream>>>(Q, ow[5], ob[5], OFF);
    deform_lds<3, 8, 4, 15, 15, 13, 13, true, 8, 12, 192, 1, false><<<dim3(B), dim3(192), 0, stream>>>(Q, OFF, w[5], bi[5], P, nullptr, nullptr);

    // ---- FC head (reads P = 512 x 4 x 13 x 13) ----
    wtrans<676, 256><<<CEILDIV(676 * 256, 256), blk, 0, stream>>>(fc1w, WT1);
    wtrans<256, 10><<<CEILDIV(256 * 10, 256), blk, 0, stream>>>(fc2w, WT2);
    fc_t<676, 256, true><<<dim3(CEILDIV(B * 256, 256)), blk, 0, stream>>>(P, WT1, fc1b, Z, B);
    fc_t<256, 10, false><<<dim3(CEILDIV(B * 10, 256)), blk, 0, stream>>>(Z, WT2, fc2b, out, B);

    #undef GRIDT
    #undef CEILDIV
}

// Round 10
// 816.104 us; speedup vs baseline: 1.3910x; 1.0037x over previous
//
#include <hip/hip_runtime.h>

typedef __attribute__((ext_vector_type(8))) short bf16x8;
typedef __attribute__((ext_vector_type(4))) float f32x4;
typedef __attribute__((ext_vector_type(2))) float f32x2;
typedef __attribute__((ext_vector_type(4))) unsigned int u32x4;
typedef unsigned short ushort_t;

__device__ inline ushort_t bf16_trunc(float f) { return (ushort_t)(__float_as_uint(f) >> 16); }
__device__ inline float bf16_to_f(ushort_t u) { return __uint_as_float(((unsigned int)u) << 16); }

// LDS-publish barrier WITHOUT vmcnt drain (verified correct r8):
// waits only lgkmcnt(0) (ds_write publish + this wave's ds_read completion)
// then raw s_barrier. Wave-private global prefetch loads stay IN FLIGHT.
__device__ inline void lds_barrier() {
    __builtin_amdgcn_sched_barrier(0);
    asm volatile("s_waitcnt lgkmcnt(0)" ::: "memory");
    __builtin_amdgcn_s_barrier();
    __builtin_amdgcn_sched_barrier(0);
}

// packed fp32 (CDNA3+): two IEEE fp32 ops per instruction
__device__ inline f32x2 pk_mul(f32x2 a, f32x2 b) {
    f32x2 d;
    asm("v_pk_mul_f32 %0, %1, %2" : "=v"(d) : "v"(a), "v"(b));
    return d;
}
__device__ inline f32x2 pk_fma(f32x2 a, f32x2 b, f32x2 c) {
    f32x2 d;
    asm("v_pk_fma_f32 %0, %1, %2, %3" : "=v"(d) : "v"(a), "v"(b), "v"(c));
    return d;
}

// pack top-16-bits of two fp32 into one u32: (u0>>16) | (u1 & 0xffff0000)
__device__ inline unsigned int hi_pair(unsigned int u1, unsigned int u0) {
    return __builtin_amdgcn_perm(u1, u0, 0x07060302u);
}

// split 8 fp32 (sA,sB) into bf16 hi + bf16 lo fragments via v_perm packing
__device__ inline void split8(const f32x4 sA, const f32x4 sB, bf16x8& ahi, bf16x8& alo)
{
    unsigned int u[8], h[8], d[8];
#pragma unroll
    for (int j = 0; j < 4; ++j) {
        u[j]     = __float_as_uint(sA[j]);
        u[4 + j] = __float_as_uint(sB[j]);
    }
#pragma unroll
    for (int j = 0; j < 8; ++j) {
        h[j] = u[j] & 0xffff0000u;                       // exact bf16-hi as f32 bits
        d[j] = __float_as_uint(__uint_as_float(u[j]) - __uint_as_float(h[j]));
    }
    union { u32x4 w; bf16x8 v; } H, L;
    H.w = (u32x4){hi_pair(h[1], h[0]), hi_pair(h[3], h[2]), hi_pair(h[5], h[4]), hi_pair(h[7], h[6])};
    L.w = (u32x4){hi_pair(d[1], d[0]), hi_pair(d[3], d[2]), hi_pair(d[5], d[4]), hi_pair(d[7], d[6])};
    ahi = H.v;
    alo = L.v;
}

// ---------------------------------------------------------------------------
// Weight prep for conv_mfma: OIHW fp32 -> [kk][n][ci] hi/lo, zero-padded.
// ---------------------------------------------------------------------------
template<int CI, int KK, int KKPAD, int NPAD, int OC>
__global__ __launch_bounds__(256)
void wprep(const float* __restrict__ w, ushort_t* __restrict__ bhi, ushort_t* __restrict__ blo)
{
    const int idx = blockIdx.x * 256 + threadIdx.x;
    if (idx >= KKPAD * NPAD * CI) return;
    const int kk  = idx / (NPAD * CI);
    const int rem = idx - kk * (NPAD * CI);
    const int n   = rem / CI;
    const int ci  = rem - n * CI;
    const float v = (kk < KK && n < OC) ? w[((size_t)n * CI + ci) * KK + kk] : 0.f;
    const ushort_t h = bf16_trunc(v);
    bhi[idx] = h;
    blo[idx] = bf16_trunc(v - bf16_to_f(h));
}

// ---------------------------------------------------------------------------
// Weight prep for deform_mfma: pack [kslot = g8*TPAD+tap][n][j=ci_in_group].
// ---------------------------------------------------------------------------
template<int CI, int KK, int TPAD, int NPAD, int OC>
__global__ __launch_bounds__(256)
void wprep_d(const float* __restrict__ w, ushort_t* __restrict__ bhi, ushort_t* __restrict__ blo)
{
    constexpr int NPASS = (CI + 7) / 8;
    constexpr int TOTAL = NPASS * TPAD * NPAD * 8;
    const int idx = blockIdx.x * 256 + threadIdx.x;
    if (idx >= TOTAL) return;
    const int j     = idx & 7;
    const int n     = (idx >> 3) % NPAD;
    const int kslot = (idx >> 3) / NPAD;
    const int pass  = kslot / TPAD;
    const int tap   = kslot - pass * TPAD;
    const int ci    = pass * 8 + j;
    const float v = (tap < KK && n < OC && ci < CI) ? w[((size_t)n * CI + ci) * KK + tap] : 0.f;
    const ushort_t h = bf16_trunc(v);
    bhi[idx] = h;
    blo[idx] = bf16_trunc(v - bf16_to_f(h));
}

// ---------------------------------------------------------------------------
// MFMA implicit-im2col conv, v9: barrier every TWO K-steps (BK=64 pairing).
//  [r8 null result] lgkm-only barrier alone was neutral -> the stall is the
//  barrier-lockstep: per-step staging chain (global ~300-600cy -> ds_write
//  -> barrier) > MFMA phase (~233cy). Pairing amortizes each barrier over
//  ~466cy of MFMA. 4 slab buffers rotate: during pair {2t,2t+1} we stage
//  pair t+1's two slabs into the OTHER two buffers (no overlap; the
//  pair-end barrier's lgkmcnt(0) orders both writers and readers).
//  A-prefetch ping-pong unchanged (loads float across barriers).
// ---------------------------------------------------------------------------
template<int CI, int K, int H, int W, int Ho, int Wo, int OC, int NTTOT, int NT0, int KSTEPS>
__global__ __launch_bounds__(256)
void conv_mfma(const ushort_t* __restrict__ Xhi, const ushort_t* __restrict__ Xlo,
               const ushort_t* __restrict__ Bhi, const ushort_t* __restrict__ Blo,
               const float* __restrict__ bias, float* __restrict__ out, int Mtotal)
{
    constexpr int NPAD = NTTOT * 16;
    constexpr int HW   = H * W;
    constexpr int HoWo = Ho * Wo;
    constexpr int NPASS = CI / 8;
    constexpr int TKS  = 32 / CI;
    constexpr int ROWS = TKS * NT0 * 16;
    constexpr int BSTR = CI + 8;
    constexpr int CH8  = CI / 8;
    constexpr int CHUNKS = ROWS * CH8;

    __shared__ __align__(16) ushort_t sBh[4][ROWS * BSTR];
    __shared__ __align__(16) ushort_t sBl[4][ROWS * BSTR];

    const int tid  = threadIdx.x;
    const int lane = tid & 63;
    const int wid  = tid >> 6;
    const int col  = lane & 15;
    const int quad = lane >> 4;

    const int mBase  = blockIdx.x * 256 + wid * 64;
    const int ntBase = blockIdx.y * NT0;

    int aBase[4];
#pragma unroll
    for (int mt = 0; mt < 4; ++mt) {
        int mm = mBase + mt * 16 + col;
        if (mm >= Mtotal) mm = Mtotal - 1;
        const int b   = mm / HoWo;
        const int pos = mm - b * HoWo;
        const int oy  = pos / Wo;
        const int ox  = pos - oy * Wo;
        aBase[mt] = b * NPASS * HW + oy * W + ox;
    }

    f32x4 acc[4][NT0];
#pragma unroll
    for (int mt = 0; mt < 4; ++mt)
#pragma unroll
        for (int nt = 0; nt < NT0; ++nt) acc[mt][nt] = (f32x4){0.f, 0.f, 0.f, 0.f};

    auto loadSlab = [&](int ks, int buf) {
        const int tap0 = ks * TKS;
        for (int i = tid; i < CHUNKS; i += 256) {
            const int row = i / CH8;
            const int c8  = i - row * CH8;
            const int t   = row / (NT0 * 16);
            const int nn  = row - t * (NT0 * 16);
            int n = ntBase * 16 + nn;
            if (n > NPAD - 1) n = NPAD - 1;
            const int g = ((tap0 + t) * NPAD + n) * CI + c8 * 8;
            *(bf16x8*)(sBh[buf] + row * BSTR + c8 * 8) = *(const bf16x8*)(Bhi + g);
            *(bf16x8*)(sBl[buf] + row * BSTR + c8 * 8) = *(const bf16x8*)(Blo + g);
        }
    };

    // double-buffered A fragments (prefetched one K-step ahead; loads stay
    // in flight across lds_barrier — no vmcnt drain)
    bf16x8 ah[2][4], al[2][4];

    auto loadA = [&](int ks, int pb) {
        const int k0   = ks * 32 + quad * 8;
        const int tap  = k0 / CI;
        const int ci   = k0 - tap * CI;
        const int g    = ci >> 3;
        const int dkk  = (tap / K) * W + (tap - (tap / K) * K);
#pragma unroll
        for (int mt = 0; mt < 4; ++mt) {
            const size_t aoff = (size_t)(aBase[mt] + g * HW + dkk) * 8;
            ah[pb][mt] = *(const bf16x8*)(Xhi + aoff);
            al[pb][mt] = *(const bf16x8*)(Xlo + aoff);
        }
    };

    loadA(0, 0);
    loadSlab(0, 0);
    if (1 < KSTEPS) loadSlab(1, 1);
    lds_barrier();

#pragma unroll
    for (int ks = 0; ks < KSTEPS; ++ks) {
        if (ks + 1 < KSTEPS) loadA(ks + 1, (ks + 1) & 1);

        // at each even step, stage the NEXT pair's two slabs into the other
        // two buffers (buffers (ks+2)&3 and (ks+3)&3 — disjoint from the
        // pair currently being read: ks&3 and (ks+1)&3)
        if ((ks & 1) == 0) {
            if (ks + 2 < KSTEPS) loadSlab(ks + 2, (ks + 2) & 3);
            if (ks + 3 < KSTEPS) loadSlab(ks + 3, (ks + 3) & 3);
        }

        const int k0   = ks * 32 + quad * 8;
        const int tap  = k0 / CI;
        const int tloc = tap - ks * TKS;
        const int ci   = k0 - tap * CI;
        const int pb   = ks & 1;
        const int sb   = ks & 3;

        const ushort_t* __restrict__ bhp = sBh[sb];
        const ushort_t* __restrict__ blp = sBl[sb];
#pragma unroll
        for (int nt = 0; nt < NT0; ++nt) {
            const int ntg = ntBase + nt;
            if (ntg < NTTOT) {
                const int lrow = ((tloc * NT0 + nt) * 16 + col) * BSTR + ci;
                const bf16x8 bh = *(const bf16x8*)(bhp + lrow);
                const bf16x8 bl = *(const bf16x8*)(blp + lrow);
#pragma unroll
                for (int mt = 0; mt < 4; ++mt) {
                    acc[mt][nt] = __builtin_amdgcn_mfma_f32_16x16x32_bf16(ah[pb][mt], bh, acc[mt][nt], 0, 0, 0);
                    acc[mt][nt] = __builtin_amdgcn_mfma_f32_16x16x32_bf16(al[pb][mt], bh, acc[mt][nt], 0, 0, 0);
                    acc[mt][nt] = __builtin_amdgcn_mfma_f32_16x16x32_bf16(ah[pb][mt], bl, acc[mt][nt], 0, 0, 0);
                }
            }
        }
        // barrier only at the end of each pair (and not after the last step)
        if ((ks & 1) == 1 && ks + 1 < KSTEPS) lds_barrier();
    }

#pragma unroll
    for (int mt = 0; mt < 4; ++mt) {
#pragma unroll
        for (int nt = 0; nt < NT0; ++nt) {
            const int ntg = ntBase + nt;
            const int n   = ntg * 16 + col;
            if (ntg < NTTOT && n < OC) {
                const float bv = bias[n];
#pragma unroll
                for (int r = 0; r < 4; ++r) {
                    const int m = mBase + mt * 16 + quad * 4 + r;
                    if (m < Mtotal) {
                        const int b   = m / HoWo;
                        const int pos = m - b * HoWo;
                        out[((size_t)b * OC + n) * HoWo + pos] = acc[mt][nt][r] + bv;
                    }
                }
            }
        }
    }
}

// ---------------------------------------------------------------------------
// MFMA deformable conv (stages 2-5), v6: single-pass staging + packed-fp32
// interp + dead-wave skip. [r5 measured: TLP-bound on LDS gather — model
// 122 µs vs 131.6 measured @ stage 3; at its structural floor.]
// ---------------------------------------------------------------------------
template<int K, int CI, int CO, int H, int W, int Ho, int Wo, bool RELU,
         int MT, int TPAD, bool OUTPL>
__global__ __launch_bounds__(MT * 64, 4)
void deform_mfma(const ushort_t* __restrict__ Xhi, const ushort_t* __restrict__ Xlo,
                 const float* __restrict__ off,
                 const ushort_t* __restrict__ Bph, const ushort_t* __restrict__ Bpl,
                 const float* __restrict__ bias,
                 float* __restrict__ outF, ushort_t* __restrict__ oHi, ushort_t* __restrict__ oLo)
{
    static_assert(CI % 8 == 0, "channel-grouped layout requires CI % 8 == 0");
    constexpr int KK     = K * K;
    constexpr int HW     = H * W;
    constexpr int HoWo   = Ho * Wo;
    constexpr int GP     = CI / 8;          // 8-channel groups, all staged at once
    constexpr int NPO    = CO / 8;
    constexpr int NT     = (CO + 15) / 16;
    constexpr int NPAD   = NT * 16;
    constexpr int TSTR   = CI + 4;          // floats per position (mult of 4)
    constexpr int TG     = TPAD / 4;
    constexpr int nMB    = (HoWo + MT * 16 - 1) / (MT * 16);
    constexpr int THREADS = MT * 64;
    __shared__ __align__(16) float tile[HW * TSTR];

    const int b    = blockIdx.x / nMB;
    const int mb   = blockIdx.x - b * nMB;
    const int tid  = threadIdx.x;
    const int wid  = tid >> 6;
    const int lane = tid & 63;
    const int col  = lane & 15;
    const int quad = lane >> 4;

    const int pixel0 = (mb * MT + wid) * 16;
    const int s      = pixel0 + col;
    const bool am    = (s < HoWo);
    const int oy = s / Wo, ox = s - oy * Wo;

    const float* offB = off + (size_t)b * 2 * KK * HoWo;

    f32x4 acc[NT];
#pragma unroll
    for (int nt = 0; nt < NT; ++nt) acc[nt] = (f32x4){0.f, 0.f, 0.f, 0.f};

    // ---- stage the full CI-channel input image into LDS (one pass) ----
    for (int pos = tid; pos < HW; pos += THREADS) {
        float* tp = tile + pos * TSTR;
#pragma unroll
        for (int g = 0; g < GP; ++g) {
            const size_t gbase = ((size_t)(b * GP + g) * HW + pos) * 8;
            const bf16x8 h8 = *(const bf16x8*)(Xhi + gbase);
            const bf16x8 l8 = *(const bf16x8*)(Xlo + gbase);
            f32x4 vA, vB;
#pragma unroll
            for (int j = 0; j < 4; ++j) {
                vA[j] = bf16_to_f((ushort_t)h8[j])     + bf16_to_f((ushort_t)l8[j]);
                vB[j] = bf16_to_f((ushort_t)h8[4 + j]) + bf16_to_f((ushort_t)l8[4 + j]);
            }
            *(f32x4*)(tp + g * 8)     = vA;
            *(f32x4*)(tp + g * 8 + 4) = vB;
        }
    }
    __syncthreads();

    if (pixel0 < HoWo) {      // dead-wave skip (wave-uniform; no barrier below)
#pragma unroll
        for (int tg = 0; tg < TG; ++tg) {
            const int tap = tg * 4 + quad;

            float w00 = 0.f, w01 = 0.f, w10 = 0.f, w11 = 0.f;
            int   i00 = 0,   i01 = 0,   i10 = 0,   i11 = 0;

            if (am && tap < KK) {
                const float dy = offB[(size_t)(2 * tap + 0) * HoWo + s];
                const float dx = offB[(size_t)(2 * tap + 1) * HoWo + s];
                const float py = (float)(tap / K + oy) + dy;
                const float px = (float)(tap % K + ox) + dx;
                const float y0f = floorf(py), x0f = floorf(px);
                const float wy = py - y0f, wx = px - x0f;
                const int y0 = (int)y0f, x0 = (int)x0f;
                const int y1 = y0 + 1,   x1 = x0 + 1;

                const float m00 = (y0 >= 0 && y0 < H && x0 >= 0 && x0 < W) ? 1.f : 0.f;
                const float m01 = (y0 >= 0 && y0 < H && x1 >= 0 && x1 < W) ? 1.f : 0.f;
                const float m10 = (y1 >= 0 && y1 < H && x0 >= 0 && x0 < W) ? 1.f : 0.f;
                const float m11 = (y1 >= 0 && y1 < H && x1 >= 0 && x1 < W) ? 1.f : 0.f;

                w00 = (1.f - wy) * (1.f - wx) * m00;
                w01 = (1.f - wy) * wx         * m01;
                w10 = wy         * (1.f - wx) * m10;
                w11 = wy         * wx         * m11;

                const int y0c = min(max(y0, 0), H - 1), y1c = min(max(y1, 0), H - 1);
                const int x0c = min(max(x0, 0), W - 1), x1c = min(max(x1, 0), W - 1);
                i00 = (y0c * W + x0c) * TSTR;
                i01 = (y0c * W + x1c) * TSTR;
                i10 = (y1c * W + x0c) * TSTR;
                i11 = (y1c * W + x1c) * TSTR;
            }

            const f32x2 w00p = {w00, w00}, w01p = {w01, w01};
            const f32x2 w10p = {w10, w10}, w11p = {w11, w11};

#pragma unroll
            for (int g = 0; g < GP; ++g) {
                const float* tp = tile + g * 8;
                const f32x4 a00 = *(const f32x4*)(tp + i00);
                const f32x4 c00 = *(const f32x4*)(tp + i00 + 4);
                const f32x4 a01 = *(const f32x4*)(tp + i01);
                const f32x4 c01 = *(const f32x4*)(tp + i01 + 4);
                const f32x4 a10 = *(const f32x4*)(tp + i10);
                const f32x4 c10 = *(const f32x4*)(tp + i10 + 4);
                const f32x4 a11 = *(const f32x4*)(tp + i11);
                const f32x4 c11 = *(const f32x4*)(tp + i11 + 4);

#define LOH(v) __builtin_shufflevector(v, v, 0, 1)
#define HIH(v) __builtin_shufflevector(v, v, 2, 3)
                f32x2 sA0 = pk_mul(LOH(a00), w00p);
                sA0 = pk_fma(LOH(a01), w01p, sA0);
                sA0 = pk_fma(LOH(a10), w10p, sA0);
                sA0 = pk_fma(LOH(a11), w11p, sA0);
                f32x2 sA1 = pk_mul(HIH(a00), w00p);
                sA1 = pk_fma(HIH(a01), w01p, sA1);
                sA1 = pk_fma(HIH(a10), w10p, sA1);
                sA1 = pk_fma(HIH(a11), w11p, sA1);
                f32x2 sB0 = pk_mul(LOH(c00), w00p);
                sB0 = pk_fma(LOH(c01), w01p, sB0);
                sB0 = pk_fma(LOH(c10), w10p, sB0);
                sB0 = pk_fma(LOH(c11), w11p, sB0);
                f32x2 sB1 = pk_mul(HIH(c00), w00p);
                sB1 = pk_fma(HIH(c01), w01p, sB1);
                sB1 = pk_fma(HIH(c10), w10p, sB1);
                sB1 = pk_fma(HIH(c11), w11p, sB1);
#undef LOH
#undef HIH
                const f32x4 sA = __builtin_shufflevector(sA0, sA1, 0, 1, 2, 3);
                const f32x4 sB = __builtin_shufflevector(sB0, sB1, 0, 1, 2, 3);

                bf16x8 ahi, alo;
                split8(sA, sB, ahi, alo);

                const int kslot = g * TPAD + tap;
#pragma unroll
                for (int nt = 0; nt < NT; ++nt) {
                    const bf16x8 bh = *(const bf16x8*)(Bph + ((size_t)kslot * NPAD + nt * 16 + col) * 8);
                    const bf16x8 bl = *(const bf16x8*)(Bpl + ((size_t)kslot * NPAD + nt * 16 + col) * 8);
                    acc[nt] = __builtin_amdgcn_mfma_f32_16x16x32_bf16(ahi, bh, acc[nt], 0, 0, 0);
                    acc[nt] = __builtin_amdgcn_mfma_f32_16x16x32_bf16(alo, bh, acc[nt], 0, 0, 0);
                    acc[nt] = __builtin_amdgcn_mfma_f32_16x16x32_bf16(ahi, bl, acc[nt], 0, 0, 0);
                }
            }
        }
    }

#pragma unroll
    for (int nt = 0; nt < NT; ++nt) {
        const int n = nt * 16 + col;
        if (n < CO) {
            const float bv = bias[n];
#pragma unroll
            for (int r = 0; r < 4; ++r) {
                const int m = pixel0 + quad * 4 + r;
                if (m < HoWo) {
                    float v = acc[nt][r] + bv;
                    if (RELU) v = fmaxf(v, 0.f);
                    if (OUTPL) {
                        const size_t o = (((size_t)b * NPO + (n >> 3)) * HoWo + m) * 8 + (n & 7);
                        const ushort_t h = bf16_trunc(v);
                        oHi[o] = h;
                        oLo[o] = bf16_trunc(v - bf16_to_f(h));
                    } else {
                        outF[((size_t)b * CO + n) * HoWo + m] = v;
                    }
                }
            }
        }
    }
}

// ---------------------------------------------------------------------------
// Scalar LDS deform (stages 1 and 6). Reads fp32 NCHW. Epilogue writes
// grouped planes (OUTPL, stage 1) or fp32 NCHW (stage 6).
// ---------------------------------------------------------------------------
template<int K, int CI, int CO, int H, int W, int Ho, int Wo, bool RELU,
         int CSPLIT, int STRIDE, int THREADS, int SPLIT, bool OUTPL>
__global__ __launch_bounds__(THREADS)
void deform_lds(const float* __restrict__ x, const float* __restrict__ off,
                const float* __restrict__ w, const float* __restrict__ bias,
                float* __restrict__ outF, ushort_t* __restrict__ oHi, ushort_t* __restrict__ oLo)
{
    constexpr int KK    = K * K;
    constexpr int HW    = H * W;
    constexpr int HoWo  = Ho * Wo;
    constexpr int NPASS = CI / CSPLIT;
    constexpr int NPO   = (CO + 7) / 8;
    constexpr int CHUNK = (HoWo + SPLIT - 1) / SPLIT;
    static_assert(CHUNK <= THREADS, "chunk must fit in one block");
    __shared__ __align__(16) float tile[HW * STRIDE];

    const int b   = blockIdx.x / SPLIT;
    const int sp  = blockIdx.x - b * SPLIT;
    const int tid = threadIdx.x;
    const int s   = sp * CHUNK + tid;
    const bool active = (tid < CHUNK) && (s < HoWo);

    const int oy = s / Wo, ox = s - oy * Wo;
    const float* offp = off + ((size_t)b * 2 * KK) * HoWo + s;

    float acc[CO];
#pragma unroll
    for (int o = 0; o < CO; ++o) acc[o] = 0.f;

    for (int pass = 0; pass < NPASS; ++pass) {
        const int cbase = pass * CSPLIT;
        __syncthreads();
        for (int pos = tid; pos < HW; pos += THREADS) {
#pragma unroll
            for (int c = 0; c < CSPLIT; ++c)
                tile[pos * STRIDE + c] = x[((size_t)b * CI + (cbase + c)) * HW + pos];
        }
        __syncthreads();

        if (active) {
            for (int kk = 0; kk < KK; ++kk) {
                const float dy = offp[(size_t)(2 * kk + 0) * HoWo];
                const float dx = offp[(size_t)(2 * kk + 1) * HoWo];
                const float py = (float)(kk / K + oy) + dy;
                const float px = (float)(kk % K + ox) + dx;
                const float y0f = floorf(py), x0f = floorf(px);
                const float wy = py - y0f, wx = px - x0f;
                const int y0 = (int)y0f, x0 = (int)x0f;
                const int y1 = y0 + 1,   x1 = x0 + 1;

                const float m00 = (y0 >= 0 && y0 < H && x0 >= 0 && x0 < W) ? 1.f : 0.f;
                const float m01 = (y0 >= 0 && y0 < H && x1 >= 0 && x1 < W) ? 1.f : 0.f;
                const float m10 = (y1 >= 0 && y1 < H && x0 >= 0 && x0 < W) ? 1.f : 0.f;
                const float m11 = (y1 >= 0 && y1 < H && x1 >= 0 && x1 < W) ? 1.f : 0.f;

                const float w00 = (1.f - wy) * (1.f - wx) * m00;
                const float w01 = (1.f - wy) * wx         * m01;
                const float w10 = wy         * (1.f - wx) * m10;
                const float w11 = wy         * wx         * m11;

                const int y0c = min(max(y0, 0), H - 1), y1c = min(max(y1, 0), H - 1);
                const int x0c = min(max(x0, 0), W - 1), x1c = min(max(x1, 0), W - 1);
                const int i00 = (y0c * W + x0c) * STRIDE;
                const int i01 = (y0c * W + x1c) * STRIDE;
                const int i10 = (y1c * W + x0c) * STRIDE;
                const int i11 = (y1c * W + x1c) * STRIDE;

                if constexpr (CSPLIT % 4 == 0) {
#pragma unroll
                    for (int cg = 0; cg < CSPLIT; cg += 4) {
                        const f32x4 v00 = *(const f32x4*)(tile + i00 + cg);
                        const f32x4 v01 = *(const f32x4*)(tile + i01 + cg);
                        const f32x4 v10 = *(const f32x4*)(tile + i10 + cg);
                        const f32x4 v11 = *(const f32x4*)(tile + i11 + cg);
#pragma unroll
                        for (int j = 0; j < 4; ++j) {
                            const float sv = fmaf(v11[j], w11, fmaf(v10[j], w10,
                                             fmaf(v01[j], w01, v00[j] * w00)));
#pragma unroll
                            for (int o = 0; o < CO; ++o)
                                acc[o] = fmaf(sv, w[(size_t)(o * CI + cbase + cg + j) * KK + kk], acc[o]);
                        }
                    }
                } else {
                    const float sv = fmaf(tile[i11], w11, fmaf(tile[i10], w10,
                                     fmaf(tile[i01], w01, tile[i00] * w00)));
#pragma unroll
                    for (int o = 0; o < CO; ++o)
                        acc[o] = fmaf(sv, w[(size_t)(o * CI + cbase) * KK + kk], acc[o]);
                }
            }
        }
    }

    if (active) {
#pragma unroll
        for (int o = 0; o < CO; ++o) {
            float v = acc[o] + bias[o];
            if (RELU) v = fmaxf(v, 0.f);
            if (OUTPL) {
                const size_t oi = (((size_t)b * NPO + (o >> 3)) * HoWo + s) * 8 + (o & 7);
                const ushort_t h = bf16_trunc(v);
                oHi[oi] = h;
                oLo[oi] = bf16_trunc(v - bf16_to_f(h));
            } else {
                outF[((size_t)b * CO + o) * HoWo + s] = v;
            }
        }
    }
}

// ---------------------------------------------------------------------------
// Register-tiled direct VALID conv (stages 1 and 6 offset convs).
// ---------------------------------------------------------------------------
template<int K, int CI, int NOC, int OC, int H, int W, int Ho, int Wo, int PIX>
__global__ __launch_bounds__(256)
void conv_tile(const float* __restrict__ x, const float* __restrict__ w,
               const float* __restrict__ bias, float* __restrict__ out)
{
    constexpr int KK   = K * K;
    constexpr int HoWo = Ho * Wo;
    constexpr int WoG  = (Wo + PIX - 1) / PIX;
    constexpr int G    = Ho * WoG;
    constexpr int XV   = PIX + K - 1;

    const int oc0   = blockIdx.y * NOC;
    const int g_all = blockIdx.x * 256 + threadIdx.x;
    const int b     = g_all / G;
    const int g     = g_all - b * G;
    const int oy    = g / WoG;
    const int ox0   = (g - oy * WoG) * PIX;

    const float* xbp = x + (b * CI) * (H * W) + oy * W + ox0;
    const float* wp  = w + oc0 * (CI * KK);

    float acc[PIX][NOC];
#pragma unroll
    for (int p = 0; p < PIX; ++p)
#pragma unroll
        for (int j = 0; j < NOC; ++j) acc[p][j] = bias[oc0 + j];

    const int lim = W - 1 - ox0;

    for (int ci = 0; ci < CI; ++ci) {
        const float* xc = xbp + ci * (H * W);
#pragma unroll
        for (int ky = 0; ky < K; ++ky) {
            float xv[XV];
#pragma unroll
            for (int i = 0; i < XV; ++i) {
                const int off = (i <= lim) ? i : lim;
                xv[i] = xc[ky * W + off];
            }
#pragma unroll
            for (int kx = 0; kx < K; ++kx) {
#pragma unroll
                for (int p = 0; p < PIX; ++p) {
                    const float v = xv[p + kx];
#pragma unroll
                    for (int j = 0; j < NOC; ++j)
                        acc[p][j] = fmaf(v, wp[j * (CI * KK) + ci * KK + ky * K + kx], acc[p][j]);
                }
            }
        }
    }

    float* op = out + (b * OC + oc0) * HoWo + oy * Wo + ox0;
#pragma unroll
    for (int p = 0; p < PIX; ++p) {
        if (ox0 + p < Wo) {
#pragma unroll
            for (int j = 0; j < NOC; ++j) op[j * HoWo + p] = acc[p][j];
        }
    }
}

// ---------------------------------------------------------------------------
// FC weight transpose + coalesced FC.
// ---------------------------------------------------------------------------
template<int IN, int OUT>
__global__ __launch_bounds__(256)
void wtrans(const float* __restrict__ w, float* __restrict__ wt)
{
    const int idx = blockIdx.x * 256 + threadIdx.x;
    if (idx >= IN * OUT) return;
    const int i = idx / OUT, j = idx - i * OUT;
    wt[idx] = w[(size_t)j * IN + i];
}

template<int IN, int OUT, bool RELU>
__global__ __launch_bounds__(256)
void fc_t(const float* __restrict__ h, const float* __restrict__ wt,
          const float* __restrict__ bias, float* __restrict__ out, int B)
{
    const int idx = blockIdx.x * 256 + threadIdx.x;
    if (idx >= B * OUT) return;
    const int b = idx / OUT;
    const int j = idx - b * OUT;
    const float* hb = h + (size_t)b * IN;
    float acc = bias[j];
#pragma unroll 4
    for (int i = 0; i < IN; ++i)
        acc = fmaf(hb[i], wt[(size_t)i * OUT + j], acc);
    if (RELU) acc = fmaxf(acc, 0.f);
    out[idx] = acc;
}

// ---------------------------------------------------------------------------
extern "C" void kernel_launch(void* const* d_in, const int* in_sizes, int n_in,
                              void* d_out, int out_size, void* d_ws, size_t ws_size,
                              hipStream_t stream)
{
    const int B = 512;
    const float* x = (const float*)d_in[0];
    const float *ow[6], *ob[6], *w[6], *bi[6];
    for (int i = 0; i < 6; ++i) {
        ow[i] = (const float*)d_in[1 + 4 * i];
        ob[i] = (const float*)d_in[2 + 4 * i];
        w[i]  = (const float*)d_in[3 + 4 * i];
        bi[i] = (const float*)d_in[4 + 4 * i];
    }
    const float* fc1w = (const float*)d_in[25];
    const float* fc1b = (const float*)d_in[26];
    const float* fc2w = (const float*)d_in[27];
    const float* fc2b = (const float*)d_in[28];
    float* out = (float*)d_out;

    float* P   = (float*)d_ws;        // 14M floats
    float* Q   = P  + 14000000;       // 14M floats
    float* OFF = Q  + 14000000;       // 18.2M floats
    float* Z   = OFF + 18200000;      // fc intermediate
    ushort_t* WBhi = (ushort_t*)(Z + 200000);
    ushort_t* WBlo = WBhi + 200000;
    ushort_t* WDhi = WBlo + 200000;
    ushort_t* WDlo = WDhi + 200000;
    float* WT1 = (float*)(WDlo + 200000);
    float* WT2 = WT1 + 173056;

    const dim3 blk(256);
    #define GRIDT(Ho, Wo, PIX, NG) dim3((B * (Ho) * (((Wo) + (PIX) - 1) / (PIX)) + 255) / 256, (NG), 1)
    #define CEILDIV(a, b) (((a) + (b) - 1) / (b))

    // plane regions (channel-grouped layout)
    ushort_t* PL2h = (ushort_t*)Q;  ushort_t* PL2l = PL2h + (size_t)(B * 961 + 2048) * 16;
    ushort_t* PL3h = (ushort_t*)P;  ushort_t* PL3l = PL3h + (size_t)(B * 841 + 2048) * 32;
    ushort_t* PL4h = (ushort_t*)Q;  ushort_t* PL4l = PL4h + (size_t)(B * 625 + 2048) * 16;
    ushort_t* PL5h = (ushort_t*)P;  ushort_t* PL5l = PL5h + (size_t)(B * 361 + 2048) * 16;

    // ---- stage 1: input x (CI=1). conv_tile -> OFF; deform_lds -> PL2 ----
    conv_tile<3, 1, 6, 18, 33, 33, 31, 31, 4><<<GRIDT(31, 31, 4, 3), blk, 0, stream>>>(x, ow[0], ob[0], OFF);
    deform_lds<3, 1, 16, 33, 33, 31, 31, true, 1, 1, 512, 2, true><<<dim3(B * 2), dim3(512), 0, stream>>>(x, OFF, w[0], bi[0], nullptr, PL2h, PL2l);

    // ---- stage 2: CI=16 K=3 31x31->29x29 OC(off)=18 CO=32. PL2 -> PL3 ----
    {
        const int Mv = B * 841;
        wprep<16, 9, 10, 32, 18><<<CEILDIV(10 * 32 * 16, 256), blk, 0, stream>>>(ow[1], WBhi, WBlo);
        conv_mfma<16, 3, 31, 31, 29, 29, 18, 2, 2, 5><<<dim3(CEILDIV(Mv, 256), 1), blk, 0, stream>>>(PL2h, PL2l, WBhi, WBlo, ob[1], OFF, Mv);
        wprep_d<16, 9, 12, 32, 32><<<CEILDIV(2 * 12 * 32 * 8, 256), blk, 0, stream>>>(w[1], WDhi, WDlo);
        deform_mfma<3, 16, 32, 31, 31, 29, 29, true, 8, 12, true><<<dim3(B * 7), dim3(512), 0, stream>>>(PL2h, PL2l, OFF, WDhi, WDlo, bi[1], nullptr, PL3h, PL3l);
    }
    // ---- stage 3: CI=32 K=5 29x29->25x25 OC(off)=50 CO=16 (no relu). PL3 -> PL4 ----
    {
        const int Mv = B * 625;
        wprep<32, 25, 25, 64, 50><<<CEILDIV(25 * 64 * 32, 256), blk, 0, stream>>>(ow[2], WBhi, WBlo);
        conv_mfma<32, 5, 29, 29, 25, 25, 50, 4, 4, 25><<<dim3(CEILDIV(Mv, 256), 1), blk, 0, stream>>>(PL3h, PL3l, WBhi, WBlo, ob[2], OFF, Mv);
        wprep_d<32, 25, 28, 16, 16><<<CEILDIV(4 * 28 * 16 * 8, 256), blk, 0, stream>>>(w[2], WDhi, WDlo);
        deform_mfma<5, 32, 16, 29, 29, 25, 25, false, 14, 28, true><<<dim3(B * 3), dim3(896), 0, stream>>>(PL3h, PL3l, OFF, WDhi, WDlo, bi[2], nullptr, PL4h, PL4l);
    }
    // ---- stage 4: CI=16 K=7 25x25->19x19 OC(off)=98 CO=16. PL4 -> PL5 ----
    {
        const int Mv = B * 361;
        wprep<16, 49, 50, 112, 98><<<CEILDIV(50 * 112 * 16, 256), blk, 0, stream>>>(ow[3], WBhi, WBlo);
        conv_mfma<16, 7, 25, 25, 19, 19, 98, 7, 4, 25><<<dim3(CEILDIV(Mv, 256), 2), blk, 0, stream>>>(PL4h, PL4l, WBhi, WBlo, ob[3], OFF, Mv);
        wprep_d<16, 49, 52, 16, 16><<<CEILDIV(2 * 52 * 16 * 8, 256), blk, 0, stream>>>(w[3], WDhi, WDlo);
        deform_mfma<7, 16, 16, 25, 25, 19, 19, true, 8, 52, true><<<dim3(B * 3), dim3(512), 0, stream>>>(PL4h, PL4l, OFF, WDhi, WDlo, bi[3], nullptr, PL5h, PL5l);
    }
    // ---- stage 5: CI=16 K=5 19x19->15x15 OC(off)=50 CO=8. PL5 -> Q (fp32 NCHW) ----
    {
        const int Mv = B * 225;
        wprep<16, 25, 26, 64, 50><<<CEILDIV(26 * 64 * 16, 256), blk, 0, stream>>>(ow[4], WBhi, WBlo);
        conv_mfma<16, 5, 19, 19, 15, 15, 50, 4, 4, 13><<<dim3(CEILDIV(Mv, 256), 1), blk, 0, stream>>>(PL5h, PL5l, WBhi, WBlo, ob[4], OFF, Mv);
        wprep_d<16, 25, 28, 16, 8><<<CEILDIV(2 * 28 * 16 * 8, 256), blk, 0, stream>>>(w[4], WDhi, WDlo);
        deform_mfma<5, 16, 8, 19, 19, 15, 15, true, 4, 28, false><<<dim3(B * 4), dim3(256), 0, stream>>>(PL5h, PL5l, OFF, WDhi, WDlo, bi[4], Q, nullptr, nullptr);
    }
    // ---- stage 6: CI=8 K=3 15x15->13x13 CO=4. Q -> P (fp32 NCHW) ----
    conv_tile<3, 8, 6, 18, 15, 15, 13, 13, 4><<<GRIDT(13, 13, 4, 3), blk, 0, stream>>>(Q, ow[5], ob[5], OFF);
    deform_lds<3, 8, 4, 15, 15, 13, 13, true, 8, 12, 192, 1, false><<<dim3(B), dim3(192), 0, stream>>>(Q, OFF, w[5], bi[5], P, nullptr, nullptr);

    // ---- FC head (reads P = 512 x 4 x 13 x 13) ----
    wtrans<676, 256><<<CEILDIV(676 * 256, 256), blk, 0, stream>>>(fc1w, WT1);
    wtrans<256, 10><<<CEILDIV(256 * 10, 256), blk, 0, stream>>>(fc2w, WT2);
    fc_t<676, 256, true><<<dim3(CEILDIV(B * 256, 256)), blk, 0, stream>>>(P, WT1, fc1b, Z, B);
    fc_t<256, 10, false><<<dim3(CEILDIV(B * 10, 256)), blk, 0, stream>>>(Z, WT2, fc2b, out, B);

    #undef GRIDT
    #undef CEILDIV
}